// Round 1
// baseline (5610.897 us; speedup 1.0000x reference)
//
#include <hip/hip_runtime.h>
#include <hip/hip_bf16.h>
#include <stdint.h>

#define NN 50000
#define NE 800000
#define HD 128
#define NL 3
#define EPS_BN 1e-5f
#define EPS_NORM 1e-12f
#define NEG_SLOPE 0.1f

static __device__ __forceinline__ unsigned pack_bf16(float a, float b) {
  unsigned ua = __builtin_bit_cast(unsigned, a);
  unsigned ub = __builtin_bit_cast(unsigned, b);
  ua = (ua + 0x7fffu + ((ua >> 16) & 1u)) >> 16;   // RNE to bf16
  ub = (ub + 0x7fffu + ((ub >> 16) & 1u)) >> 16;
  return ua | (ub << 16);
}
static __device__ __forceinline__ float bflo(unsigned u) { return __builtin_bit_cast(float, u << 16); }
static __device__ __forceinline__ float bfhi(unsigned u) { return __builtin_bit_cast(float, u & 0xffff0000u); }

// ---------------- degree ----------------
__global__ __launch_bounds__(256) void deg_kernel(const int* __restrict__ dst, float* __restrict__ deg) {
  int i = blockIdx.x * 256 + threadIdx.x;
  if (i < NE) atomicAdd(&deg[dst[i]], 1.0f);
}
__global__ __launch_bounds__(256) void invdeg_kernel(float* __restrict__ deg) {
  int i = blockIdx.x * 256 + threadIdx.x;
  if (i < NN) deg[i] = 1.0f / fmaxf(deg[i], 1.0f);
}

// ---------------- scatter-add aggregation ----------------
// 32 threads per edge, each handles 4 consecutive feats (float4 gather + 4 atomics)
__global__ __launch_bounds__(256) void scatter_kernel(const float* __restrict__ x,
                                                      const int* __restrict__ src,
                                                      const int* __restrict__ dst,
                                                      float* __restrict__ agg) {
  int gid = blockIdx.x * 256 + threadIdx.x;  // total = NE*32
  int e = gid >> 5;
  int q = gid & 31;
  int s = src[e];
  int d = dst[e];
  float4 v = *(const float4*)(x + (size_t)s * HD + q * 4);
  float* o = agg + (size_t)d * HD + q * 4;
  atomicAdd(o + 0, v.x);
  atomicAdd(o + 1, v.y);
  atomicAdd(o + 2, v.z);
  atomicAdd(o + 3, v.w);
}

// ---------------- fused: pre = L2norm(aggn@Wl^T + bl + x@Wr^T); stats ----------------
// Weights staged transposed [k][f] as packed bf16 pairs, padded rows of 66 u32.
// 512 threads: rp = tid>>5 (16 row-groups of 4 rows), fg = tid&31 (4 feats each).
__global__ __launch_bounds__(512) void gemm_pre_kernel(
    float* __restrict__ agg, const float* __restrict__ x,
    const float* __restrict__ Wl, const float* __restrict__ Wr,
    const float* __restrict__ bl, const float* __restrict__ invdeg,
    float* __restrict__ colsum, float* __restrict__ colsumsq) {
  __shared__ float xs[64][HD];
  __shared__ float as_[64][HD];
  __shared__ unsigned wl_s[HD * 66];
  __shared__ unsigned wr_s[HD * 66];

  const int tid = threadIdx.x;
  for (int i = tid; i < HD * 64; i += 512) {
    int m = i >> 7;   // feat-pair 0..63
    int k = i & 127;  // coalesced along k
    wl_s[k * 66 + m] = pack_bf16(Wl[(2 * m) * HD + k], Wl[(2 * m + 1) * HD + k]);
    wr_s[k * 66 + m] = pack_bf16(Wr[(2 * m) * HD + k], Wr[(2 * m + 1) * HD + k]);
  }

  const int rp = tid >> 5;
  const int fg = tid & 31;
  const float4 blv = *(const float4*)(bl + fg * 4);

  float cs[4] = {0.f, 0.f, 0.f, 0.f}, cq[4] = {0.f, 0.f, 0.f, 0.f};

  const int ntiles = (NN + 63) >> 6;
  for (int tile = blockIdx.x; tile < ntiles; tile += gridDim.x) {
    const int r0 = tile << 6;
    __syncthreads();  // protect LDS from previous iter readers (also fences weight stage)
    for (int i = tid; i < 64 * 32; i += 512) {
      int r = i >> 5, c = i & 31;
      int row = r0 + r;
      float4 xv = {0.f, 0.f, 0.f, 0.f}, av = {0.f, 0.f, 0.f, 0.f};
      if (row < NN) {
        xv = *(const float4*)(x + (size_t)row * HD + c * 4);
        av = *(const float4*)(agg + (size_t)row * HD + c * 4);
        float id = invdeg[row];
        av.x *= id; av.y *= id; av.z *= id; av.w *= id;
      }
      *(float4*)&xs[r][c * 4] = xv;
      *(float4*)&as_[r][c * 4] = av;
    }
    __syncthreads();

    float acc[4][4];
#pragma unroll
    for (int i = 0; i < 4; ++i) {
      acc[i][0] = blv.x; acc[i][1] = blv.y; acc[i][2] = blv.z; acc[i][3] = blv.w;
    }

    for (int k4 = 0; k4 < HD; k4 += 4) {
      float4 a4[4], x4[4];
#pragma unroll
      for (int i = 0; i < 4; ++i) {
        a4[i] = *(const float4*)&as_[rp * 4 + i][k4];
        x4[i] = *(const float4*)&xs[rp * 4 + i][k4];
      }
#pragma unroll
      for (int kk = 0; kk < 4; ++kk) {
        int k = k4 + kk;
        unsigned l0 = wl_s[k * 66 + fg * 2], l1 = wl_s[k * 66 + fg * 2 + 1];
        unsigned q0 = wr_s[k * 66 + fg * 2], q1 = wr_s[k * 66 + fg * 2 + 1];
        float wl0 = bflo(l0), wl1 = bfhi(l0), wl2 = bflo(l1), wl3 = bfhi(l1);
        float wr0 = bflo(q0), wr1 = bfhi(q0), wr2 = bflo(q1), wr3 = bfhi(q1);
#pragma unroll
        for (int i = 0; i < 4; ++i) {
          float a = (&a4[i].x)[kk];
          float xv = (&x4[i].x)[kk];
          acc[i][0] = fmaf(a, wl0, fmaf(xv, wr0, acc[i][0]));
          acc[i][1] = fmaf(a, wl1, fmaf(xv, wr1, acc[i][1]));
          acc[i][2] = fmaf(a, wl2, fmaf(xv, wr2, acc[i][2]));
          acc[i][3] = fmaf(a, wl3, fmaf(xv, wr3, acc[i][3]));
        }
      }
    }

#pragma unroll
    for (int i = 0; i < 4; ++i) {
      int row = r0 + rp * 4 + i;
      float ss = acc[i][0] * acc[i][0] + acc[i][1] * acc[i][1] +
                 acc[i][2] * acc[i][2] + acc[i][3] * acc[i][3];
#pragma unroll
      for (int m = 16; m >= 1; m >>= 1) ss += __shfl_xor(ss, m, 64);
      float inv = 1.0f / fmaxf(sqrtf(ss), EPS_NORM);
      float p0 = acc[i][0] * inv, p1 = acc[i][1] * inv, p2 = acc[i][2] * inv, p3 = acc[i][3] * inv;
      if (row < NN) {
        *(float4*)(agg + (size_t)row * HD + fg * 4) = make_float4(p0, p1, p2, p3);
        cs[0] += p0; cs[1] += p1; cs[2] += p2; cs[3] += p3;
        cq[0] += p0 * p0; cq[1] += p1 * p1; cq[2] += p2 * p2; cq[3] += p3 * p3;
      }
    }
  }
  atomicAdd(&colsum[fg * 4 + 0], cs[0]);
  atomicAdd(&colsum[fg * 4 + 1], cs[1]);
  atomicAdd(&colsum[fg * 4 + 2], cs[2]);
  atomicAdd(&colsum[fg * 4 + 3], cs[3]);
  atomicAdd(&colsumsq[fg * 4 + 0], cq[0]);
  atomicAdd(&colsumsq[fg * 4 + 1], cq[1]);
  atomicAdd(&colsumsq[fg * 4 + 2], cq[2]);
  atomicAdd(&colsumsq[fg * 4 + 3], cq[3]);
}

// ---------------- finalize BN stats ----------------
__global__ __launch_bounds__(HD) void finalize_kernel(
    const float* __restrict__ colsum, const float* __restrict__ colsumsq,
    const float* __restrict__ gamma, const float* __restrict__ beta,
    float* __restrict__ scale, float* __restrict__ shift) {
  int f = threadIdx.x;
  float mu = colsum[f] * (1.0f / NN);
  float ex2 = colsumsq[f] * (1.0f / NN);
  float var = ex2 - mu * mu;
  float sc = gamma[f] * rsqrtf(var + EPS_BN);
  scale[f] = sc;
  shift[f] = beta[f] - mu * sc;
}

// ---------------- out = lrelu(BN(pre)) + x@Ws^T + bs ----------------
__global__ __launch_bounds__(512) void res_bn_kernel(
    const float* __restrict__ x, const float* __restrict__ pre,
    const float* __restrict__ Wsm, const float* __restrict__ bs,
    const float* __restrict__ scale, const float* __restrict__ shift,
    float* __restrict__ xout) {
  __shared__ float xs[64][HD];
  __shared__ unsigned ws_s[HD * 66];
  const int tid = threadIdx.x;
  for (int i = tid; i < HD * 64; i += 512) {
    int m = i >> 7;
    int k = i & 127;
    ws_s[k * 66 + m] = pack_bf16(Wsm[(2 * m) * HD + k], Wsm[(2 * m + 1) * HD + k]);
  }
  const int rp = tid >> 5;
  const int fg = tid & 31;
  const float4 bs4 = *(const float4*)(bs + fg * 4);
  const float4 sc4 = *(const float4*)(scale + fg * 4);
  const float4 sh4 = *(const float4*)(shift + fg * 4);

  const int ntiles = (NN + 63) >> 6;
  for (int tile = blockIdx.x; tile < ntiles; tile += gridDim.x) {
    const int r0 = tile << 6;
    __syncthreads();
    for (int i = tid; i < 64 * 32; i += 512) {
      int r = i >> 5, c = i & 31;
      int row = r0 + r;
      float4 xv = {0.f, 0.f, 0.f, 0.f};
      if (row < NN) xv = *(const float4*)(x + (size_t)row * HD + c * 4);
      *(float4*)&xs[r][c * 4] = xv;
    }
    __syncthreads();

    float acc[4][4];
#pragma unroll
    for (int i = 0; i < 4; ++i) {
      acc[i][0] = bs4.x; acc[i][1] = bs4.y; acc[i][2] = bs4.z; acc[i][3] = bs4.w;
    }

    for (int k4 = 0; k4 < HD; k4 += 4) {
      float4 x4[4];
#pragma unroll
      for (int i = 0; i < 4; ++i) x4[i] = *(const float4*)&xs[rp * 4 + i][k4];
#pragma unroll
      for (int kk = 0; kk < 4; ++kk) {
        int k = k4 + kk;
        unsigned w0 = ws_s[k * 66 + fg * 2], w1 = ws_s[k * 66 + fg * 2 + 1];
        float f0 = bflo(w0), f1 = bfhi(w0), f2 = bflo(w1), f3 = bfhi(w1);
#pragma unroll
        for (int i = 0; i < 4; ++i) {
          float xv = (&x4[i].x)[kk];
          acc[i][0] = fmaf(xv, f0, acc[i][0]);
          acc[i][1] = fmaf(xv, f1, acc[i][1]);
          acc[i][2] = fmaf(xv, f2, acc[i][2]);
          acc[i][3] = fmaf(xv, f3, acc[i][3]);
        }
      }
    }

#pragma unroll
    for (int i = 0; i < 4; ++i) {
      int row = r0 + rp * 4 + i;
      if (row < NN) {
        float4 p = *(const float4*)(pre + (size_t)row * HD + fg * 4);
        float v0 = p.x * sc4.x + sh4.x; v0 = v0 >= 0.f ? v0 : NEG_SLOPE * v0;
        float v1 = p.y * sc4.y + sh4.y; v1 = v1 >= 0.f ? v1 : NEG_SLOPE * v1;
        float v2 = p.z * sc4.z + sh4.z; v2 = v2 >= 0.f ? v2 : NEG_SLOPE * v2;
        float v3 = p.w * sc4.w + sh4.w; v3 = v3 >= 0.f ? v3 : NEG_SLOPE * v3;
        *(float4*)(xout + (size_t)row * HD + fg * 4) =
            make_float4(v0 + acc[i][0], v1 + acc[i][1], v2 + acc[i][2], v3 + acc[i][3]);
      }
    }
  }
}

extern "C" void kernel_launch(void* const* d_in, const int* in_sizes, int n_in,
                              void* d_out, int out_size, void* d_ws, size_t ws_size,
                              hipStream_t stream) {
  const float* x0    = (const float*)d_in[0];
  const int*   ei    = (const int*)d_in[1];
  const float* Wl    = (const float*)d_in[2];
  const float* bl    = (const float*)d_in[3];
  const float* Wr    = (const float*)d_in[4];
  const float* gamma = (const float*)d_in[5];
  const float* beta  = (const float*)d_in[6];
  const float* Wsm   = (const float*)d_in[7];
  const float* bs    = (const float*)d_in[8];
  float* out = (float*)d_out;

  float* ws       = (float*)d_ws;
  float* agg      = ws;                          // N*H (also holds "pre" after gemm_pre)
  float* xbuf     = agg + (size_t)NN * HD;       // N*H
  float* deg      = xbuf + (size_t)NN * HD;      // N  (becomes invdeg)
  float* colsum   = deg + NN;                    // H
  float* colsumsq = colsum + HD;                 // H
  float* scale    = colsumsq + HD;               // H
  float* shift    = scale + HD;                  // H

  const int* src = ei;
  const int* dst = ei + NE;

  hipMemsetAsync(deg, 0, NN * sizeof(float), stream);
  deg_kernel<<<(NE + 255) / 256, 256, 0, stream>>>(dst, deg);
  invdeg_kernel<<<(NN + 255) / 256, 256, 0, stream>>>(deg);

  const float* xin = x0;
  for (int l = 0; l < NL; ++l) {
    float* xout = (l == NL - 1) ? out : xbuf;
    hipMemsetAsync(agg, 0, (size_t)NN * HD * sizeof(float), stream);
    hipMemsetAsync(colsum, 0, 2 * HD * sizeof(float), stream);
    scatter_kernel<<<(NE * 32) / 256, 256, 0, stream>>>(xin, src, dst, agg);
    gemm_pre_kernel<<<256, 512, 0, stream>>>(agg, xin,
                                             Wl + (size_t)l * HD * HD,
                                             Wr + (size_t)l * HD * HD,
                                             bl + (size_t)l * HD,
                                             deg, colsum, colsumsq);
    finalize_kernel<<<1, HD, 0, stream>>>(colsum, colsumsq,
                                          gamma + (size_t)l * HD, beta + (size_t)l * HD,
                                          scale, shift);
    res_bn_kernel<<<512, 512, 0, stream>>>(xin, agg, Wsm, bs, scale, shift, xout);
    xin = xout;
  }
}

// Round 3
// 1913.314 us; speedup vs baseline: 2.9326x; 2.9326x over previous
//
#include <hip/hip_runtime.h>
#include <hip/hip_bf16.h>
#include <stdint.h>

#define NN 50000
#define NE 800000
#define HD 128
#define NL 3
#define EPS_BN 1e-5f
#define EPS_NORM 1e-12f
#define NEG_SLOPE 0.1f

static __device__ __forceinline__ unsigned pack_bf16(float a, float b) {
  unsigned ua = __builtin_bit_cast(unsigned, a);
  unsigned ub = __builtin_bit_cast(unsigned, b);
  ua = (ua + 0x7fffu + ((ua >> 16) & 1u)) >> 16;   // RNE to bf16
  ub = (ub + 0x7fffu + ((ub >> 16) & 1u)) >> 16;
  return ua | (ub << 16);
}
static __device__ __forceinline__ float bflo(unsigned u) { return __builtin_bit_cast(float, u << 16); }
static __device__ __forceinline__ float bfhi(unsigned u) { return __builtin_bit_cast(float, u & 0xffff0000u); }

// ---------------- CSR build ----------------
__global__ __launch_bounds__(256) void hist_kernel(const int* __restrict__ dst, int* __restrict__ degi) {
  int i = blockIdx.x * 256 + threadIdx.x;
  if (i < NE) atomicAdd(&degi[dst[i]], 1);
}

// single block of 1024: exclusive scan of degi -> rowptr; init cursor; invdeg
__global__ __launch_bounds__(1024) void scan_kernel(const int* __restrict__ degi,
                                                    int* __restrict__ rowptr,
                                                    int* __restrict__ cursor,
                                                    float* __restrict__ invdeg) {
  __shared__ int partial[1024];
  const int C = 49;  // 1024*49 = 50176 >= NN
  const int t = threadIdx.x;
  const int base = t * C;
  int s = 0;
  for (int i = 0; i < C; ++i) {
    int idx = base + i;
    if (idx < NN) s += degi[idx];
  }
  partial[t] = s;
  __syncthreads();
  for (int off = 1; off < 1024; off <<= 1) {
    int v = (t >= off) ? partial[t - off] : 0;
    __syncthreads();
    if (t >= off) partial[t] += v;
    __syncthreads();
  }
  int run = (t == 0) ? 0 : partial[t - 1];
  for (int i = 0; i < C; ++i) {
    int idx = base + i;
    if (idx < NN) {
      rowptr[idx] = run;
      cursor[idx] = run;
      int d = degi[idx];
      invdeg[idx] = 1.0f / fmaxf((float)d, 1.0f);
      run += d;
    }
  }
  if (t == 1023) rowptr[NN] = partial[1023];
}

__global__ __launch_bounds__(256) void fill_kernel(const int* __restrict__ src,
                                                   const int* __restrict__ dst,
                                                   int* __restrict__ cursor,
                                                   int* __restrict__ esrc) {
  int e = blockIdx.x * 256 + threadIdx.x;
  if (e < NE) {
    int pos = atomicAdd(&cursor[dst[e]], 1);
    esrc[pos] = src[e];
  }
}

// ---------------- gather-side aggregation: one wave per node ----------------
__global__ __launch_bounds__(512) void agg_csr_kernel(const float* __restrict__ x,
                                                      const int* __restrict__ rowptr,
                                                      const int* __restrict__ esrc,
                                                      const float* __restrict__ invdeg,
                                                      float* __restrict__ agg) {
  int node = (blockIdx.x * 512 + threadIdx.x) >> 6;
  int lane = threadIdx.x & 63;
  if (node >= NN) return;
  int start = rowptr[node], end = rowptr[node + 1];
  float2 acc = {0.f, 0.f};
  int e = start;
  for (; e + 4 <= end; e += 4) {
    int s0 = esrc[e], s1 = esrc[e + 1], s2 = esrc[e + 2], s3 = esrc[e + 3];
    float2 v0 = *(const float2*)(x + (size_t)s0 * HD + lane * 2);
    float2 v1 = *(const float2*)(x + (size_t)s1 * HD + lane * 2);
    float2 v2 = *(const float2*)(x + (size_t)s2 * HD + lane * 2);
    float2 v3 = *(const float2*)(x + (size_t)s3 * HD + lane * 2);
    acc.x += (v0.x + v1.x) + (v2.x + v3.x);
    acc.y += (v0.y + v1.y) + (v2.y + v3.y);
  }
  for (; e < end; ++e) {
    int s = esrc[e];
    float2 v = *(const float2*)(x + (size_t)s * HD + lane * 2);
    acc.x += v.x;
    acc.y += v.y;
  }
  float id = invdeg[node];
  *(float2*)(agg + (size_t)node * HD + lane * 2) = make_float2(acc.x * id, acc.y * id);
}

// ---------------- fused: pre = L2norm(agg@Wl^T + bl + x@Wr^T); stats ----------------
__global__ __launch_bounds__(512) void gemm_pre_kernel(
    float* __restrict__ agg, const float* __restrict__ x,
    const float* __restrict__ Wl, const float* __restrict__ Wr,
    const float* __restrict__ bl,
    float* __restrict__ colsum, float* __restrict__ colsumsq) {
  __shared__ float xs[64][HD];
  __shared__ float as_[64][HD];
  __shared__ unsigned wl_s[HD * 66];
  __shared__ unsigned wr_s[HD * 66];

  const int tid = threadIdx.x;
  for (int i = tid; i < HD * 64; i += 512) {
    int m = i >> 7;   // feat-pair 0..63
    int k = i & 127;  // coalesced along k
    wl_s[k * 66 + m] = pack_bf16(Wl[(2 * m) * HD + k], Wl[(2 * m + 1) * HD + k]);
    wr_s[k * 66 + m] = pack_bf16(Wr[(2 * m) * HD + k], Wr[(2 * m + 1) * HD + k]);
  }

  const int rp = tid >> 5;
  const int fg = tid & 31;
  const float4 blv = *(const float4*)(bl + fg * 4);

  float cs[4] = {0.f, 0.f, 0.f, 0.f}, cq[4] = {0.f, 0.f, 0.f, 0.f};

  const int ntiles = (NN + 63) >> 6;
  for (int tile = blockIdx.x; tile < ntiles; tile += gridDim.x) {
    const int r0 = tile << 6;
    __syncthreads();
    for (int i = tid; i < 64 * 32; i += 512) {
      int r = i >> 5, c = i & 31;
      int row = r0 + r;
      float4 xv = {0.f, 0.f, 0.f, 0.f}, av = {0.f, 0.f, 0.f, 0.f};
      if (row < NN) {
        xv = *(const float4*)(x + (size_t)row * HD + c * 4);
        av = *(const float4*)(agg + (size_t)row * HD + c * 4);
      }
      *(float4*)&xs[r][c * 4] = xv;
      *(float4*)&as_[r][c * 4] = av;
    }
    __syncthreads();

    float acc[4][4];
#pragma unroll
    for (int i = 0; i < 4; ++i) {
      acc[i][0] = blv.x; acc[i][1] = blv.y; acc[i][2] = blv.z; acc[i][3] = blv.w;
    }

    for (int k4 = 0; k4 < HD; k4 += 4) {
      float4 a4[4], x4[4];
#pragma unroll
      for (int i = 0; i < 4; ++i) {
        a4[i] = *(const float4*)&as_[rp * 4 + i][k4];
        x4[i] = *(const float4*)&xs[rp * 4 + i][k4];
      }
#pragma unroll
      for (int kk = 0; kk < 4; ++kk) {
        int k = k4 + kk;
        unsigned l0 = wl_s[k * 66 + fg * 2], l1 = wl_s[k * 66 + fg * 2 + 1];
        unsigned q0 = wr_s[k * 66 + fg * 2], q1 = wr_s[k * 66 + fg * 2 + 1];
        float wl0 = bflo(l0), wl1 = bfhi(l0), wl2 = bflo(l1), wl3 = bfhi(l1);
        float wr0 = bflo(q0), wr1 = bfhi(q0), wr2 = bflo(q1), wr3 = bfhi(q1);
#pragma unroll
        for (int i = 0; i < 4; ++i) {
          float a = (&a4[i].x)[kk];
          float xv = (&x4[i].x)[kk];
          acc[i][0] = fmaf(a, wl0, fmaf(xv, wr0, acc[i][0]));
          acc[i][1] = fmaf(a, wl1, fmaf(xv, wr1, acc[i][1]));
          acc[i][2] = fmaf(a, wl2, fmaf(xv, wr2, acc[i][2]));
          acc[i][3] = fmaf(a, wl3, fmaf(xv, wr3, acc[i][3]));
        }
      }
    }

#pragma unroll
    for (int i = 0; i < 4; ++i) {
      int row = r0 + rp * 4 + i;
      float ss = acc[i][0] * acc[i][0] + acc[i][1] * acc[i][1] +
                 acc[i][2] * acc[i][2] + acc[i][3] * acc[i][3];
#pragma unroll
      for (int m = 16; m >= 1; m >>= 1) ss += __shfl_xor(ss, m, 64);
      float inv = 1.0f / fmaxf(sqrtf(ss), EPS_NORM);
      float p0 = acc[i][0] * inv, p1 = acc[i][1] * inv, p2 = acc[i][2] * inv, p3 = acc[i][3] * inv;
      if (row < NN) {
        *(float4*)(agg + (size_t)row * HD + fg * 4) = make_float4(p0, p1, p2, p3);
        cs[0] += p0; cs[1] += p1; cs[2] += p2; cs[3] += p3;
        cq[0] += p0 * p0; cq[1] += p1 * p1; cq[2] += p2 * p2; cq[3] += p3 * p3;
      }
    }
  }
  atomicAdd(&colsum[fg * 4 + 0], cs[0]);
  atomicAdd(&colsum[fg * 4 + 1], cs[1]);
  atomicAdd(&colsum[fg * 4 + 2], cs[2]);
  atomicAdd(&colsum[fg * 4 + 3], cs[3]);
  atomicAdd(&colsumsq[fg * 4 + 0], cq[0]);
  atomicAdd(&colsumsq[fg * 4 + 1], cq[1]);
  atomicAdd(&colsumsq[fg * 4 + 2], cq[2]);
  atomicAdd(&colsumsq[fg * 4 + 3], cq[3]);
}

// ---------------- finalize BN stats ----------------
__global__ __launch_bounds__(HD) void finalize_kernel(
    const float* __restrict__ colsum, const float* __restrict__ colsumsq,
    const float* __restrict__ gamma, const float* __restrict__ beta,
    float* __restrict__ scale, float* __restrict__ shift) {
  int f = threadIdx.x;
  float mu = colsum[f] * (1.0f / NN);
  float ex2 = colsumsq[f] * (1.0f / NN);
  float var = ex2 - mu * mu;
  float sc = gamma[f] * rsqrtf(var + EPS_BN);
  scale[f] = sc;
  shift[f] = beta[f] - mu * sc;
}

// ---------------- out = lrelu(BN(pre)) + x@Ws^T + bs ----------------
__global__ __launch_bounds__(512) void res_bn_kernel(
    const float* __restrict__ x, const float* __restrict__ pre,
    const float* __restrict__ Wsm, const float* __restrict__ bs,
    const float* __restrict__ scale, const float* __restrict__ shift,
    float* __restrict__ xout) {
  __shared__ float xs[64][HD];
  __shared__ unsigned ws_s[HD * 66];
  const int tid = threadIdx.x;
  for (int i = tid; i < HD * 64; i += 512) {
    int m = i >> 7;
    int k = i & 127;
    ws_s[k * 66 + m] = pack_bf16(Wsm[(2 * m) * HD + k], Wsm[(2 * m + 1) * HD + k]);
  }
  const int rp = tid >> 5;
  const int fg = tid & 31;
  const float4 bs4 = *(const float4*)(bs + fg * 4);
  const float4 sc4 = *(const float4*)(scale + fg * 4);
  const float4 sh4 = *(const float4*)(shift + fg * 4);

  const int ntiles = (NN + 63) >> 6;
  for (int tile = blockIdx.x; tile < ntiles; tile += gridDim.x) {
    const int r0 = tile << 6;
    __syncthreads();
    for (int i = tid; i < 64 * 32; i += 512) {
      int r = i >> 5, c = i & 31;
      int row = r0 + r;
      float4 xv = {0.f, 0.f, 0.f, 0.f};
      if (row < NN) xv = *(const float4*)(x + (size_t)row * HD + c * 4);
      *(float4*)&xs[r][c * 4] = xv;
    }
    __syncthreads();

    float acc[4][4];
#pragma unroll
    for (int i = 0; i < 4; ++i) {
      acc[i][0] = bs4.x; acc[i][1] = bs4.y; acc[i][2] = bs4.z; acc[i][3] = bs4.w;
    }

    for (int k4 = 0; k4 < HD; k4 += 4) {
      float4 x4[4];
#pragma unroll
      for (int i = 0; i < 4; ++i) x4[i] = *(const float4*)&xs[rp * 4 + i][k4];
#pragma unroll
      for (int kk = 0; kk < 4; ++kk) {
        int k = k4 + kk;
        unsigned w0 = ws_s[k * 66 + fg * 2], w1 = ws_s[k * 66 + fg * 2 + 1];
        float f0 = bflo(w0), f1 = bfhi(w0), f2 = bflo(w1), f3 = bfhi(w1);
#pragma unroll
        for (int i = 0; i < 4; ++i) {
          float xv = (&x4[i].x)[kk];
          acc[i][0] = fmaf(xv, f0, acc[i][0]);
          acc[i][1] = fmaf(xv, f1, acc[i][1]);
          acc[i][2] = fmaf(xv, f2, acc[i][2]);
          acc[i][3] = fmaf(xv, f3, acc[i][3]);
        }
      }
    }

#pragma unroll
    for (int i = 0; i < 4; ++i) {
      int row = r0 + rp * 4 + i;
      if (row < NN) {
        float4 p = *(const float4*)(pre + (size_t)row * HD + fg * 4);
        float v0 = p.x * sc4.x + sh4.x; v0 = v0 >= 0.f ? v0 : NEG_SLOPE * v0;
        float v1 = p.y * sc4.y + sh4.y; v1 = v1 >= 0.f ? v1 : NEG_SLOPE * v1;
        float v2 = p.z * sc4.z + sh4.z; v2 = v2 >= 0.f ? v2 : NEG_SLOPE * v2;
        float v3 = p.w * sc4.w + sh4.w; v3 = v3 >= 0.f ? v3 : NEG_SLOPE * v3;
        *(float4*)(xout + (size_t)row * HD + fg * 4) =
            make_float4(v0 + acc[i][0], v1 + acc[i][1], v2 + acc[i][2], v3 + acc[i][3]);
      }
    }
  }
}

extern "C" void kernel_launch(void* const* d_in, const int* in_sizes, int n_in,
                              void* d_out, int out_size, void* d_ws, size_t ws_size,
                              hipStream_t stream) {
  const float* x0    = (const float*)d_in[0];
  const int*   ei    = (const int*)d_in[1];
  const float* Wl    = (const float*)d_in[2];
  const float* bl    = (const float*)d_in[3];
  const float* Wr    = (const float*)d_in[4];
  const float* gamma = (const float*)d_in[5];
  const float* beta  = (const float*)d_in[6];
  const float* Wsm   = (const float*)d_in[7];
  const float* bs    = (const float*)d_in[8];
  float* out = (float*)d_out;

  float* ws       = (float*)d_ws;
  float* agg      = ws;                          // N*H (also "pre")
  float* xbuf     = agg + (size_t)NN * HD;       // N*H
  float* invdeg   = xbuf + (size_t)NN * HD;      // N
  float* colsum   = invdeg + NN;                 // H
  float* colsumsq = colsum + HD;                 // H
  float* scale    = colsumsq + HD;               // H
  float* shift    = scale + HD;                  // H
  int*   degi     = (int*)(shift + HD);          // N
  int*   rowptr   = degi + NN;                   // N+1
  int*   cursor   = rowptr + NN + 1;             // N
  int*   esrc     = cursor + NN;                 // E

  const int* src = ei;
  const int* dst = ei + NE;

  // ---- one-time CSR build ----
  hipMemsetAsync(degi, 0, NN * sizeof(int), stream);
  hist_kernel<<<(NE + 255) / 256, 256, 0, stream>>>(dst, degi);
  scan_kernel<<<1, 1024, 0, stream>>>(degi, rowptr, cursor, invdeg);
  fill_kernel<<<(NE + 255) / 256, 256, 0, stream>>>(src, dst, cursor, esrc);

  const float* xin = x0;
  for (int l = 0; l < NL; ++l) {
    float* xout = (l == NL - 1) ? out : xbuf;
    hipMemsetAsync(colsum, 0, 2 * HD * sizeof(float), stream);
    agg_csr_kernel<<<(NN * 64 + 511) / 512, 512, 0, stream>>>(xin, rowptr, esrc, invdeg, agg);
    gemm_pre_kernel<<<256, 512, 0, stream>>>(agg, xin,
                                             Wl + (size_t)l * HD * HD,
                                             Wr + (size_t)l * HD * HD,
                                             bl + (size_t)l * HD,
                                             colsum, colsumsq);
    finalize_kernel<<<1, HD, 0, stream>>>(colsum, colsumsq,
                                          gamma + (size_t)l * HD, beta + (size_t)l * HD,
                                          scale, shift);
    res_bn_kernel<<<512, 512, 0, stream>>>(xin, agg, Wsm, bs, scale, shift, xout);
    xin = xout;
  }
}

// Round 4
// 588.528 us; speedup vs baseline: 9.5338x; 3.2510x over previous
//
#include <hip/hip_runtime.h>
#include <hip/hip_bf16.h>
#include <stdint.h>

#define NN 50000
#define NE 800000
#define HD 128
#define NL 3
#define EPS_BN 1e-5f
#define EPS_NORM 1e-12f
#define NEG_SLOPE 0.1f

typedef __attribute__((ext_vector_type(8))) short bf16x8;
typedef __attribute__((ext_vector_type(4))) float f32x4;

static __device__ __forceinline__ unsigned pack_bf16(float a, float b) {
  unsigned ua = __builtin_bit_cast(unsigned, a);
  unsigned ub = __builtin_bit_cast(unsigned, b);
  ua = (ua + 0x7fffu + ((ua >> 16) & 1u)) >> 16;   // RNE
  ub = (ub + 0x7fffu + ((ub >> 16) & 1u)) >> 16;
  return ua | (ub << 16);
}
static __device__ __forceinline__ ushort bf16of(float f) {
  unsigned u = __builtin_bit_cast(unsigned, f);
  u = (u + 0x7fffu + ((u >> 16) & 1u)) >> 16;
  return (ushort)u;
}
static __device__ __forceinline__ float bflo(unsigned u) { return __builtin_bit_cast(float, u << 16); }
static __device__ __forceinline__ float bfhi(unsigned u) { return __builtin_bit_cast(float, u & 0xffff0000u); }
static __device__ __forceinline__ float fbf(ushort u) { return __builtin_bit_cast(float, (unsigned)u << 16); }

// ---------------- CSR build ----------------
__global__ __launch_bounds__(256) void hist_kernel(const int* __restrict__ dst, int* __restrict__ degi) {
  int i = blockIdx.x * 256 + threadIdx.x;
  if (i < NE) atomicAdd(&degi[dst[i]], 1);
}

__global__ __launch_bounds__(1024) void scan_kernel(const int* __restrict__ degi,
                                                    int* __restrict__ rowptr,
                                                    int* __restrict__ cursor,
                                                    float* __restrict__ invdeg) {
  __shared__ int partial[1024];
  const int C = 49;
  const int t = threadIdx.x;
  const int base = t * C;
  int s = 0;
  for (int i = 0; i < C; ++i) {
    int idx = base + i;
    if (idx < NN) s += degi[idx];
  }
  partial[t] = s;
  __syncthreads();
  for (int off = 1; off < 1024; off <<= 1) {
    int v = (t >= off) ? partial[t - off] : 0;
    __syncthreads();
    if (t >= off) partial[t] += v;
    __syncthreads();
  }
  int run = (t == 0) ? 0 : partial[t - 1];
  for (int i = 0; i < C; ++i) {
    int idx = base + i;
    if (idx < NN) {
      rowptr[idx] = run;
      cursor[idx] = run;
      int d = degi[idx];
      invdeg[idx] = 1.0f / fmaxf((float)d, 1.0f);
      run += d;
    }
  }
  if (t == 1023) rowptr[NN] = partial[1023];
}

__global__ __launch_bounds__(256) void fill_kernel(const int* __restrict__ src,
                                                   const int* __restrict__ dst,
                                                   int* __restrict__ cursor,
                                                   int* __restrict__ esrc) {
  int e = blockIdx.x * 256 + threadIdx.x;
  if (e < NE) {
    int pos = atomicAdd(&cursor[dst[e]], 1);
    esrc[pos] = src[e];
  }
}

// ---------------- f32 -> bf16 convert ----------------
__global__ __launch_bounds__(256) void tobf16_kernel(const float* __restrict__ x, ushort* __restrict__ xb) {
  int i = blockIdx.x * 256 + threadIdx.x;  // one u32 (2 bf16) each
  if (i < NN * 64) {
    float2 f = *(const float2*)(x + (size_t)i * 2);
    *(unsigned*)(xb + (size_t)i * 2) = pack_bf16(f.x, f.y);
  }
}

// ---------------- gather-side aggregation (bf16 in/out, f32 accum) ----------------
__global__ __launch_bounds__(512) void agg_csr_kernel(const ushort* __restrict__ xb,
                                                      const int* __restrict__ rowptr,
                                                      const int* __restrict__ esrc,
                                                      const float* __restrict__ invdeg,
                                                      ushort* __restrict__ aggb) {
  int node = (blockIdx.x * 512 + threadIdx.x) >> 6;
  int lane = threadIdx.x & 63;
  if (node >= NN) return;
  int start = rowptr[node], end = rowptr[node + 1];
  float a0 = 0.f, a1 = 0.f;
  int e = start;
  for (; e + 4 <= end; e += 4) {
    int s0 = esrc[e], s1 = esrc[e + 1], s2 = esrc[e + 2], s3 = esrc[e + 3];
    unsigned u0 = *(const unsigned*)(xb + (size_t)s0 * HD + lane * 2);
    unsigned u1 = *(const unsigned*)(xb + (size_t)s1 * HD + lane * 2);
    unsigned u2 = *(const unsigned*)(xb + (size_t)s2 * HD + lane * 2);
    unsigned u3 = *(const unsigned*)(xb + (size_t)s3 * HD + lane * 2);
    a0 += (bflo(u0) + bflo(u1)) + (bflo(u2) + bflo(u3));
    a1 += (bfhi(u0) + bfhi(u1)) + (bfhi(u2) + bfhi(u3));
  }
  for (; e < end; ++e) {
    unsigned u = *(const unsigned*)(xb + (size_t)esrc[e] * HD + lane * 2);
    a0 += bflo(u);
    a1 += bfhi(u);
  }
  float id = invdeg[node];
  *(unsigned*)(aggb + (size_t)node * HD + lane * 2) = pack_bf16(a0 * id, a1 * id);
}

// ---------------- MFMA: pre = L2norm([aggb|xb] @ [Wl|Wr]^T + bl), BN stats ----------------
// Tile: 128 rows x 128 cols, K=256. 512 thr = 8 waves, each wave 16 rows x 128 cols.
// A (activations) and B (weights as [out][in], i.e. B^T) both [row][k] bf16 in LDS,
// XOR-swizzled: byte ^= ((row&7)<<4). Writes pre bf16 IN-PLACE over aggb.
__global__ __launch_bounds__(512) void mfma_pre_kernel(
    const ushort* __restrict__ aggb, const ushort* __restrict__ xb,
    const float* __restrict__ Wl, const float* __restrict__ Wr,
    const float* __restrict__ bl, ushort* __restrict__ preb,
    float* __restrict__ colsum, float* __restrict__ colsumsq) {
  __shared__ ushort Asw[128 * 256];   // 64 KB
  __shared__ ushort Bsw[128 * 256];   // 64 KB
  __shared__ float lsum[HD];
  __shared__ float lsq[HD];
  const int tid = threadIdx.x;

  // pack weights -> LDS bf16 [c][k], swizzled
  for (int i = tid; i < 128 * 128; i += 512) {
    int c = i >> 7, kp = i & 127;
    int k2 = kp * 2;
    float f0, f1;
    if (k2 < 128) { f0 = Wl[c * HD + k2];       f1 = Wl[c * HD + k2 + 1]; }
    else          { f0 = Wr[c * HD + k2 - 128]; f1 = Wr[c * HD + k2 - 127]; }
    unsigned ba = (unsigned)(c * 512 + kp * 4) ^ (unsigned)((c & 7) << 4);
    *(unsigned*)((char*)Bsw + ba) = pack_bf16(f0, f1);
  }
  if (tid < HD) { lsum[tid] = 0.f; lsq[tid] = 0.f; }

  // stage A tile (aggb | xb), swizzled
  const int r0 = blockIdx.x * 128;
  for (int i = tid; i < 128 * 32; i += 512) {
    int r = i >> 5, ch = i & 31;
    int row = r0 + r;
    uint4 v = make_uint4(0u, 0u, 0u, 0u);
    if (row < NN) {
      if (ch < 16) v = *(const uint4*)((const char*)aggb + (size_t)row * 256 + ch * 16);
      else         v = *(const uint4*)((const char*)xb + (size_t)row * 256 + (ch - 16) * 16);
    }
    unsigned ba = (unsigned)(r * 512 + ch * 16) ^ (unsigned)((r & 7) << 4);
    *(uint4*)((char*)Asw + ba) = v;
  }
  __syncthreads();

  const int wave = tid >> 6, lane = tid & 63;
  const int lhi = lane >> 4, llo = lane & 15;
  const int rb = wave * 16;

  f32x4 acc[8];
#pragma unroll
  for (int ct = 0; ct < 8; ++ct) {
    float b = bl[ct * 16 + llo];
    acc[ct] = (f32x4){b, b, b, b};
  }

#pragma unroll
  for (int ks = 0; ks < 8; ++ks) {
    int arow = rb + llo;
    unsigned ab = (unsigned)(arow * 512 + ks * 64 + lhi * 16) ^ (unsigned)((arow & 7) << 4);
    bf16x8 a = *(const bf16x8*)((const char*)Asw + ab);
#pragma unroll
    for (int ct = 0; ct < 8; ++ct) {
      int bcol = ct * 16 + llo;
      unsigned bb = (unsigned)(bcol * 512 + ks * 64 + lhi * 16) ^ (unsigned)((bcol & 7) << 4);
      bf16x8 b = *(const bf16x8*)((const char*)Bsw + bb);
      acc[ct] = __builtin_amdgcn_mfma_f32_16x16x32_bf16(a, b, acc[ct], 0, 0, 0);
    }
  }

  float cs[8] = {0.f, 0.f, 0.f, 0.f, 0.f, 0.f, 0.f, 0.f};
  float cq[8] = {0.f, 0.f, 0.f, 0.f, 0.f, 0.f, 0.f, 0.f};
#pragma unroll
  for (int r = 0; r < 4; ++r) {
    int row = r0 + rb + lhi * 4 + r;
    float v[8];
    float ss = 0.f;
#pragma unroll
    for (int ct = 0; ct < 8; ++ct) { v[ct] = acc[ct][r]; ss += v[ct] * v[ct]; }
#pragma unroll
    for (int m = 8; m >= 1; m >>= 1) ss += __shfl_xor(ss, m, 64);
    float inv = 1.0f / fmaxf(sqrtf(ss), EPS_NORM);
    if (row < NN) {
#pragma unroll
      for (int ct = 0; ct < 8; ++ct) {
        float p = v[ct] * inv;
        preb[(size_t)row * HD + ct * 16 + llo] = bf16of(p);
        cs[ct] += p;
        cq[ct] += p * p;
      }
    }
  }
#pragma unroll
  for (int ct = 0; ct < 8; ++ct) {
    atomicAdd(&lsum[ct * 16 + llo], cs[ct]);
    atomicAdd(&lsq[ct * 16 + llo], cq[ct]);
  }
  __syncthreads();
  if (tid < HD) {
    atomicAdd(&colsum[tid], lsum[tid]);
    atomicAdd(&colsumsq[tid], lsq[tid]);
  }
}

// ---------------- finalize BN stats ----------------
__global__ __launch_bounds__(HD) void finalize_kernel(
    const float* __restrict__ colsum, const float* __restrict__ colsumsq,
    const float* __restrict__ gamma, const float* __restrict__ beta,
    float* __restrict__ scale, float* __restrict__ shift) {
  int f = threadIdx.x;
  float mu = colsum[f] * (1.0f / NN);
  float ex2 = colsumsq[f] * (1.0f / NN);
  float var = ex2 - mu * mu;
  float sc = gamma[f] * rsqrtf(var + EPS_BN);
  scale[f] = sc;
  shift[f] = beta[f] - mu * sc;
}

// ---------------- MFMA: out = lrelu(BN(pre)) + xb@Ws^T + bs ----------------
// K=128. Writes bf16 IN-PLACE over xb (last==0) or f32 to outf (last==1).
__global__ __launch_bounds__(512) void res_mfma_kernel(
    ushort* __restrict__ xb, const ushort* __restrict__ preb,
    const float* __restrict__ Wsm, const float* __restrict__ bs,
    const float* __restrict__ scale, const float* __restrict__ shift,
    float* __restrict__ outf, int last) {
  __shared__ ushort Asw[128 * 128];   // 32 KB
  __shared__ ushort Bsw[128 * 128];   // 32 KB
  const int tid = threadIdx.x;

  for (int i = tid; i < 128 * 64; i += 512) {
    int c = i >> 6, kp = i & 63;
    int k2 = kp * 2;
    unsigned ba = (unsigned)(c * 256 + kp * 4) ^ (unsigned)((c & 7) << 4);
    *(unsigned*)((char*)Bsw + ba) = pack_bf16(Wsm[c * HD + k2], Wsm[c * HD + k2 + 1]);
  }

  const int r0 = blockIdx.x * 128;
  for (int i = tid; i < 128 * 16; i += 512) {
    int r = i >> 4, ch = i & 15;
    int row = r0 + r;
    uint4 v = make_uint4(0u, 0u, 0u, 0u);
    if (row < NN) v = *(const uint4*)((const char*)xb + (size_t)row * 256 + ch * 16);
    unsigned ba = (unsigned)(r * 256 + ch * 16) ^ (unsigned)((r & 7) << 4);
    *(uint4*)((char*)Asw + ba) = v;
  }
  __syncthreads();

  const int wave = tid >> 6, lane = tid & 63;
  const int lhi = lane >> 4, llo = lane & 15;
  const int rb = wave * 16;

  f32x4 acc[8];
  float sc[8], sh[8];
#pragma unroll
  for (int ct = 0; ct < 8; ++ct) {
    int C = ct * 16 + llo;
    float b = bs[C];
    acc[ct] = (f32x4){b, b, b, b};
    sc[ct] = scale[C];
    sh[ct] = shift[C];
  }

#pragma unroll
  for (int ks = 0; ks < 4; ++ks) {
    int arow = rb + llo;
    unsigned ab = (unsigned)(arow * 256 + ks * 64 + lhi * 16) ^ (unsigned)((arow & 7) << 4);
    bf16x8 a = *(const bf16x8*)((const char*)Asw + ab);
#pragma unroll
    for (int ct = 0; ct < 8; ++ct) {
      int bcol = ct * 16 + llo;
      unsigned bb = (unsigned)(bcol * 256 + ks * 64 + lhi * 16) ^ (unsigned)((bcol & 7) << 4);
      bf16x8 b = *(const bf16x8*)((const char*)Bsw + bb);
      acc[ct] = __builtin_amdgcn_mfma_f32_16x16x32_bf16(a, b, acc[ct], 0, 0, 0);
    }
  }

#pragma unroll
  for (int r = 0; r < 4; ++r) {
    int row = r0 + rb + lhi * 4 + r;
    if (row < NN) {
#pragma unroll
      for (int ct = 0; ct < 8; ++ct) {
        int C = ct * 16 + llo;
        float pv = fbf(preb[(size_t)row * HD + C]);
        float v = pv * sc[ct] + sh[ct];
        v = v >= 0.f ? v : NEG_SLOPE * v;
        float o = v + acc[ct][r];
        if (last) outf[(size_t)row * HD + C] = o;
        else      xb[(size_t)row * HD + C] = bf16of(o);
      }
    }
  }
}

extern "C" void kernel_launch(void* const* d_in, const int* in_sizes, int n_in,
                              void* d_out, int out_size, void* d_ws, size_t ws_size,
                              hipStream_t stream) {
  const float* x0    = (const float*)d_in[0];
  const int*   ei    = (const int*)d_in[1];
  const float* Wl    = (const float*)d_in[2];
  const float* bl    = (const float*)d_in[3];
  const float* Wr    = (const float*)d_in[4];
  const float* gamma = (const float*)d_in[5];
  const float* beta  = (const float*)d_in[6];
  const float* Wsm   = (const float*)d_in[7];
  const float* bs    = (const float*)d_in[8];
  float* out = (float*)d_out;

  ushort* aggb  = (ushort*)d_ws;                  // N*H bf16 (doubles as preb)
  ushort* xb    = aggb + (size_t)NN * HD;         // N*H bf16
  float* invdeg = (float*)(xb + (size_t)NN * HD); // N
  float* colsum = invdeg + NN;                    // H
  float* colsumsq = colsum + HD;                  // H
  float* scale  = colsumsq + HD;                  // H
  float* shift  = scale + HD;                     // H
  int* degi     = (int*)(shift + HD);             // N
  int* rowptr   = degi + NN;                      // N+1
  int* cursor   = rowptr + NN + 1;                // N
  int* esrc     = cursor + NN;                    // E

  const int* src = ei;
  const int* dst = ei + NE;

  // one-time CSR build + bf16 convert
  hipMemsetAsync(degi, 0, NN * sizeof(int), stream);
  hist_kernel<<<(NE + 255) / 256, 256, 0, stream>>>(dst, degi);
  scan_kernel<<<1, 1024, 0, stream>>>(degi, rowptr, cursor, invdeg);
  fill_kernel<<<(NE + 255) / 256, 256, 0, stream>>>(src, dst, cursor, esrc);
  tobf16_kernel<<<(NN * 64 + 255) / 256, 256, 0, stream>>>(x0, xb);

  const int ntiles = (NN + 127) / 128;  // 391
  for (int l = 0; l < NL; ++l) {
    hipMemsetAsync(colsum, 0, 2 * HD * sizeof(float), stream);
    agg_csr_kernel<<<(NN * 64 + 511) / 512, 512, 0, stream>>>(xb, rowptr, esrc, invdeg, aggb);
    mfma_pre_kernel<<<ntiles, 512, 0, stream>>>(aggb, xb,
                                                Wl + (size_t)l * HD * HD,
                                                Wr + (size_t)l * HD * HD,
                                                bl + (size_t)l * HD,
                                                aggb /*preb in-place*/, colsum, colsumsq);
    finalize_kernel<<<1, HD, 0, stream>>>(colsum, colsumsq,
                                          gamma + (size_t)l * HD, beta + (size_t)l * HD,
                                          scale, shift);
    res_mfma_kernel<<<ntiles, 512, 0, stream>>>(xb, aggb, Wsm, bs, scale, shift,
                                                out, l == NL - 1 ? 1 : 0);
  }
}

// Round 6
// 446.991 us; speedup vs baseline: 12.5526x; 1.3166x over previous
//
#include <hip/hip_runtime.h>
#include <hip/hip_bf16.h>
#include <stdint.h>

#define NN 50000
#define NE 800000
#define HD 128
#define NL 3
#define EPS_BN 1e-5f
#define EPS_NORM 1e-12f
#define NEG_SLOPE 0.1f

#define SCAN_CHUNK 256
#define SCAN_BLOCKS ((NN + SCAN_CHUNK - 1) / SCAN_CHUNK)   // 196

typedef __attribute__((ext_vector_type(8))) short bf16x8;
typedef __attribute__((ext_vector_type(4))) float f32x4;

static __device__ __forceinline__ unsigned pack_bf16(float a, float b) {
  unsigned ua = __builtin_bit_cast(unsigned, a);
  unsigned ub = __builtin_bit_cast(unsigned, b);
  ua = (ua + 0x7fffu + ((ua >> 16) & 1u)) >> 16;   // RNE
  ub = (ub + 0x7fffu + ((ub >> 16) & 1u)) >> 16;
  return ua | (ub << 16);
}
static __device__ __forceinline__ ushort bf16of(float f) {
  unsigned u = __builtin_bit_cast(unsigned, f);
  u = (u + 0x7fffu + ((u >> 16) & 1u)) >> 16;
  return (ushort)u;
}
static __device__ __forceinline__ float bflo(unsigned u) { return __builtin_bit_cast(float, u << 16); }
static __device__ __forceinline__ float bfhi(unsigned u) { return __builtin_bit_cast(float, u & 0xffff0000u); }
static __device__ __forceinline__ float fbf(ushort u) { return __builtin_bit_cast(float, (unsigned)u << 16); }

// ---------------- CSR build ----------------
__global__ __launch_bounds__(256) void hist_kernel(const int* __restrict__ dst, int* __restrict__ degi) {
  int i = blockIdx.x * 256 + threadIdx.x;
  if (i < NE) atomicAdd(&degi[dst[i]], 1);
}

// A: per-block sums of degi
__global__ __launch_bounds__(256) void blocksum_kernel(const int* __restrict__ degi,
                                                       int* __restrict__ blocksum) {
  __shared__ int sh[256];
  int t = threadIdx.x;
  int i = blockIdx.x * 256 + t;
  sh[t] = (i < NN) ? degi[i] : 0;
  __syncthreads();
  for (int off = 128; off >= 1; off >>= 1) {
    if (t < off) sh[t] += sh[t + off];
    __syncthreads();
  }
  if (t == 0) blocksum[blockIdx.x] = sh[0];
}

// B: 1-block exclusive scan of blocksums (196 -> pad 256); writes rowptr[NN]
__global__ __launch_bounds__(256) void blockscan_kernel(int* __restrict__ blocksum,
                                                        int* __restrict__ blockoff,
                                                        int* __restrict__ rowptr) {
  __shared__ int sh[256];
  int t = threadIdx.x;
  int v = (t < SCAN_BLOCKS) ? blocksum[t] : 0;
  sh[t] = v;
  __syncthreads();
  for (int off = 1; off < 256; off <<= 1) {
    int u = (t >= off) ? sh[t - off] : 0;
    __syncthreads();
    sh[t] += u;
    __syncthreads();
  }
  if (t < SCAN_BLOCKS) blockoff[t] = sh[t] - v;  // exclusive
  if (t == 255) rowptr[NN] = sh[255];
}

// C: per-block exclusive scan + offset; write rowptr/cursor/invdeg
__global__ __launch_bounds__(256) void chunkscan_kernel(const int* __restrict__ degi,
                                                        const int* __restrict__ blockoff,
                                                        int* __restrict__ rowptr,
                                                        int* __restrict__ cursor,
                                                        float* __restrict__ invdeg) {
  __shared__ int sh[256];
  int t = threadIdx.x;
  int i = blockIdx.x * 256 + t;
  int d = (i < NN) ? degi[i] : 0;
  sh[t] = d;
  __syncthreads();
  for (int off = 1; off < 256; off <<= 1) {
    int u = (t >= off) ? sh[t - off] : 0;
    __syncthreads();
    sh[t] += u;
    __syncthreads();
  }
  if (i < NN) {
    int pre = blockoff[blockIdx.x] + sh[t] - d;  // exclusive prefix
    rowptr[i] = pre;
    cursor[i] = pre;
    invdeg[i] = 1.0f / fmaxf((float)d, 1.0f);
  }
}

__global__ __launch_bounds__(256) void fill_kernel(const int* __restrict__ src,
                                                   const int* __restrict__ dst,
                                                   int* __restrict__ cursor,
                                                   int* __restrict__ esrc) {
  int e = blockIdx.x * 256 + threadIdx.x;
  if (e < NE) {
    int pos = atomicAdd(&cursor[dst[e]], 1);
    esrc[pos] = src[e];
  }
}

// ---------------- f32 -> bf16 convert ----------------
__global__ __launch_bounds__(256) void tobf16_kernel(const float* __restrict__ x, ushort* __restrict__ xb) {
  int i = blockIdx.x * 256 + threadIdx.x;  // one u32 (2 bf16) each
  if (i < NN * 64) {
    float2 f = *(const float2*)(x + (size_t)i * 2);
    *(unsigned*)(xb + (size_t)i * 2) = pack_bf16(f.x, f.y);
  }
}

// ---------------- gather-side aggregation (bf16 in/out, f32 accum) ----------------
__global__ __launch_bounds__(512) void agg_csr_kernel(const ushort* __restrict__ xb,
                                                      const int* __restrict__ rowptr,
                                                      const int* __restrict__ esrc,
                                                      const float* __restrict__ invdeg,
                                                      ushort* __restrict__ aggb) {
  int node = (blockIdx.x * 512 + threadIdx.x) >> 6;
  int lane = threadIdx.x & 63;
  if (node >= NN) return;
  int start = rowptr[node], end = rowptr[node + 1];
  float a0 = 0.f, a1 = 0.f;
  int e = start;
  for (; e + 4 <= end; e += 4) {
    int s0 = esrc[e], s1 = esrc[e + 1], s2 = esrc[e + 2], s3 = esrc[e + 3];
    unsigned u0 = *(const unsigned*)(xb + (size_t)s0 * HD + lane * 2);
    unsigned u1 = *(const unsigned*)(xb + (size_t)s1 * HD + lane * 2);
    unsigned u2 = *(const unsigned*)(xb + (size_t)s2 * HD + lane * 2);
    unsigned u3 = *(const unsigned*)(xb + (size_t)s3 * HD + lane * 2);
    a0 += (bflo(u0) + bflo(u1)) + (bflo(u2) + bflo(u3));
    a1 += (bfhi(u0) + bfhi(u1)) + (bfhi(u2) + bfhi(u3));
  }
  for (; e < end; ++e) {
    unsigned u = *(const unsigned*)(xb + (size_t)esrc[e] * HD + lane * 2);
    a0 += bflo(u);
    a1 += bfhi(u);
  }
  float id = invdeg[node];
  *(unsigned*)(aggb + (size_t)node * HD + lane * 2) = pack_bf16(a0 * id, a1 * id);
}

// ---------------- MFMA: pre = L2norm([aggb|xb] @ [Wl|Wr]^T + bl), BN stats ----------------
__global__ __launch_bounds__(512) void mfma_pre_kernel(
    const ushort* __restrict__ aggb, const ushort* __restrict__ xb,
    const float* __restrict__ Wl, const float* __restrict__ Wr,
    const float* __restrict__ bl, ushort* __restrict__ preb,
    float* __restrict__ colsum, float* __restrict__ colsumsq) {
  __shared__ ushort Asw[128 * 256];   // 64 KB
  __shared__ ushort Bsw[128 * 256];   // 64 KB
  __shared__ float lsum[HD];
  __shared__ float lsq[HD];
  const int tid = threadIdx.x;

  // pack weights -> LDS bf16 [c][k], swizzled
  for (int i = tid; i < 128 * 128; i += 512) {
    int c = i >> 7, kp = i & 127;
    int k2 = kp * 2;
    float f0, f1;
    if (k2 < 128) { f0 = Wl[c * HD + k2];       f1 = Wl[c * HD + k2 + 1]; }
    else          { f0 = Wr[c * HD + k2 - 128]; f1 = Wr[c * HD + k2 - 127]; }
    unsigned ba = (unsigned)(c * 512 + kp * 4) ^ (unsigned)((c & 7) << 4);
    *(unsigned*)((char*)Bsw + ba) = pack_bf16(f0, f1);
  }
  if (tid < HD) { lsum[tid] = 0.f; lsq[tid] = 0.f; }

  // stage A tile (aggb | xb), swizzled
  const int r0 = blockIdx.x * 128;
  for (int i = tid; i < 128 * 32; i += 512) {
    int r = i >> 5, ch = i & 31;
    int row = r0 + r;
    uint4 v = make_uint4(0u, 0u, 0u, 0u);
    if (row < NN) {
      if (ch < 16) v = *(const uint4*)((const char*)aggb + (size_t)row * 256 + ch * 16);
      else         v = *(const uint4*)((const char*)xb + (size_t)row * 256 + (ch - 16) * 16);
    }
    unsigned ba = (unsigned)(r * 512 + ch * 16) ^ (unsigned)((r & 7) << 4);
    *(uint4*)((char*)Asw + ba) = v;
  }
  __syncthreads();

  const int wave = tid >> 6, lane = tid & 63;
  const int lhi = lane >> 4, llo = lane & 15;
  const int rb = wave * 16;

  f32x4 acc[8];
#pragma unroll
  for (int ct = 0; ct < 8; ++ct) {
    float b = bl[ct * 16 + llo];
    acc[ct] = (f32x4){b, b, b, b};
  }

#pragma unroll
  for (int ks = 0; ks < 8; ++ks) {
    int arow = rb + llo;
    unsigned ab = (unsigned)(arow * 512 + ks * 64 + lhi * 16) ^ (unsigned)((arow & 7) << 4);
    bf16x8 a = *(const bf16x8*)((const char*)Asw + ab);
#pragma unroll
    for (int ct = 0; ct < 8; ++ct) {
      int bcol = ct * 16 + llo;
      unsigned bb = (unsigned)(bcol * 512 + ks * 64 + lhi * 16) ^ (unsigned)((bcol & 7) << 4);
      bf16x8 b = *(const bf16x8*)((const char*)Bsw + bb);
      acc[ct] = __builtin_amdgcn_mfma_f32_16x16x32_bf16(a, b, acc[ct], 0, 0, 0);
    }
  }

  float cs[8] = {0.f, 0.f, 0.f, 0.f, 0.f, 0.f, 0.f, 0.f};
  float cq[8] = {0.f, 0.f, 0.f, 0.f, 0.f, 0.f, 0.f, 0.f};
#pragma unroll
  for (int r = 0; r < 4; ++r) {
    int row = r0 + rb + lhi * 4 + r;
    float v[8];
    float ss = 0.f;
#pragma unroll
    for (int ct = 0; ct < 8; ++ct) { v[ct] = acc[ct][r]; ss += v[ct] * v[ct]; }
#pragma unroll
    for (int m = 8; m >= 1; m >>= 1) ss += __shfl_xor(ss, m, 64);
    float inv = 1.0f / fmaxf(sqrtf(ss), EPS_NORM);
    if (row < NN) {
#pragma unroll
      for (int ct = 0; ct < 8; ++ct) {
        float p = v[ct] * inv;
        preb[(size_t)row * HD + ct * 16 + llo] = bf16of(p);
        cs[ct] += p;
        cq[ct] += p * p;
      }
    }
  }
#pragma unroll
  for (int ct = 0; ct < 8; ++ct) {
    atomicAdd(&lsum[ct * 16 + llo], cs[ct]);
    atomicAdd(&lsq[ct * 16 + llo], cq[ct]);
  }
  __syncthreads();
  if (tid < HD) {
    atomicAdd(&colsum[tid], lsum[tid]);
    atomicAdd(&colsumsq[tid], lsq[tid]);
  }
}

// ---------------- finalize BN stats ----------------
__global__ __launch_bounds__(HD) void finalize_kernel(
    const float* __restrict__ colsum, const float* __restrict__ colsumsq,
    const float* __restrict__ gamma, const float* __restrict__ beta,
    float* __restrict__ scale, float* __restrict__ shift) {
  int f = threadIdx.x;
  float mu = colsum[f] * (1.0f / NN);
  float ex2 = colsumsq[f] * (1.0f / NN);
  float var = ex2 - mu * mu;
  float sc = gamma[f] * rsqrtf(var + EPS_BN);
  scale[f] = sc;
  shift[f] = beta[f] - mu * sc;
}

// ---------------- MFMA: out = lrelu(BN(pre)) + xb@Ws^T + bs ----------------
__global__ __launch_bounds__(512) void res_mfma_kernel(
    ushort* __restrict__ xb, const ushort* __restrict__ preb,
    const float* __restrict__ Wsm, const float* __restrict__ bs,
    const float* __restrict__ scale, const float* __restrict__ shift,
    float* __restrict__ outf, int last) {
  __shared__ ushort Asw[128 * 128];   // 32 KB
  __shared__ ushort Bsw[128 * 128];   // 32 KB
  const int tid = threadIdx.x;

  for (int i = tid; i < 128 * 64; i += 512) {
    int c = i >> 6, kp = i & 63;
    int k2 = kp * 2;
    unsigned ba = (unsigned)(c * 256 + kp * 4) ^ (unsigned)((c & 7) << 4);
    *(unsigned*)((char*)Bsw + ba) = pack_bf16(Wsm[c * HD + k2], Wsm[c * HD + k2 + 1]);
  }

  const int r0 = blockIdx.x * 128;
  for (int i = tid; i < 128 * 16; i += 512) {
    int r = i >> 4, ch = i & 15;
    int row = r0 + r;
    uint4 v = make_uint4(0u, 0u, 0u, 0u);
    if (row < NN) v = *(const uint4*)((const char*)xb + (size_t)row * 256 + ch * 16);
    unsigned ba = (unsigned)(r * 256 + ch * 16) ^ (unsigned)((r & 7) << 4);
    *(uint4*)((char*)Asw + ba) = v;
  }
  __syncthreads();

  const int wave = tid >> 6, lane = tid & 63;
  const int lhi = lane >> 4, llo = lane & 15;
  const int rb = wave * 16;

  f32x4 acc[8];
  float sc[8], sh[8];
#pragma unroll
  for (int ct = 0; ct < 8; ++ct) {
    int C = ct * 16 + llo;
    float b = bs[C];
    acc[ct] = (f32x4){b, b, b, b};
    sc[ct] = scale[C];
    sh[ct] = shift[C];
  }

#pragma unroll
  for (int ks = 0; ks < 4; ++ks) {
    int arow = rb + llo;
    unsigned ab = (unsigned)(arow * 256 + ks * 64 + lhi * 16) ^ (unsigned)((arow & 7) << 4);
    bf16x8 a = *(const bf16x8*)((const char*)Asw + ab);
#pragma unroll
    for (int ct = 0; ct < 8; ++ct) {
      int bcol = ct * 16 + llo;
      unsigned bb = (unsigned)(bcol * 256 + ks * 64 + lhi * 16) ^ (unsigned)((bcol & 7) << 4);
      bf16x8 b = *(const bf16x8*)((const char*)Bsw + bb);
      acc[ct] = __builtin_amdgcn_mfma_f32_16x16x32_bf16(a, b, acc[ct], 0, 0, 0);
    }
  }

#pragma unroll
  for (int r = 0; r < 4; ++r) {
    int row = r0 + rb + lhi * 4 + r;
    if (row < NN) {
#pragma unroll
      for (int ct = 0; ct < 8; ++ct) {
        int C = ct * 16 + llo;
        float pv = fbf(preb[(size_t)row * HD + C]);
        float v = pv * sc[ct] + sh[ct];
        v = v >= 0.f ? v : NEG_SLOPE * v;
        float o = v + acc[ct][r];
        if (last) outf[(size_t)row * HD + C] = o;
        else      xb[(size_t)row * HD + C] = bf16of(o);
      }
    }
  }
}

extern "C" void kernel_launch(void* const* d_in, const int* in_sizes, int n_in,
                              void* d_out, int out_size, void* d_ws, size_t ws_size,
                              hipStream_t stream) {
  const float* x0    = (const float*)d_in[0];
  const int*   ei    = (const int*)d_in[1];
  const float* Wl    = (const float*)d_in[2];
  const float* bl    = (const float*)d_in[3];
  const float* Wr    = (const float*)d_in[4];
  const float* gamma = (const float*)d_in[5];
  const float* beta  = (const float*)d_in[6];
  const float* Wsm   = (const float*)d_in[7];
  const float* bs    = (const float*)d_in[8];
  float* out = (float*)d_out;

  ushort* aggb  = (ushort*)d_ws;                  // N*H bf16 (doubles as preb)
  ushort* xb    = aggb + (size_t)NN * HD;         // N*H bf16
  float* invdeg = (float*)(xb + (size_t)NN * HD); // N
  float* colsum = invdeg + NN;                    // H
  float* colsumsq = colsum + HD;                  // H
  float* scale  = colsumsq + HD;                  // H
  float* shift  = scale + HD;                     // H
  int* degi     = (int*)(shift + HD);             // N
  int* rowptr   = degi + NN;                      // N+1
  int* cursor   = rowptr + NN + 1;                // N
  int* blocksum = cursor + NN;                    // SCAN_BLOCKS
  int* blockoff = blocksum + SCAN_BLOCKS;         // SCAN_BLOCKS
  int* esrc     = blockoff + SCAN_BLOCKS;         // E

  const int* src = ei;
  const int* dst = ei + NE;

  // one-time CSR build + bf16 convert
  hipMemsetAsync(degi, 0, NN * sizeof(int), stream);
  hist_kernel<<<(NE + 255) / 256, 256, 0, stream>>>(dst, degi);
  blocksum_kernel<<<SCAN_BLOCKS, 256, 0, stream>>>(degi, blocksum);
  blockscan_kernel<<<1, 256, 0, stream>>>(blocksum, blockoff, rowptr);
  chunkscan_kernel<<<SCAN_BLOCKS, 256, 0, stream>>>(degi, blockoff, rowptr, cursor, invdeg);
  fill_kernel<<<(NE + 255) / 256, 256, 0, stream>>>(src, dst, cursor, esrc);
  tobf16_kernel<<<(NN * 64 + 255) / 256, 256, 0, stream>>>(x0, xb);

  const int ntiles = (NN + 127) / 128;  // 391
  for (int l = 0; l < NL; ++l) {
    hipMemsetAsync(colsum, 0, 2 * HD * sizeof(float), stream);
    agg_csr_kernel<<<(NN * 64 + 511) / 512, 512, 0, stream>>>(xb, rowptr, esrc, invdeg, aggb);
    mfma_pre_kernel<<<ntiles, 512, 0, stream>>>(aggb, xb,
                                                Wl + (size_t)l * HD * HD,
                                                Wr + (size_t)l * HD * HD,
                                                bl + (size_t)l * HD,
                                                aggb /*preb in-place*/, colsum, colsumsq);
    finalize_kernel<<<1, HD, 0, stream>>>(colsum, colsumsq,
                                          gamma + (size_t)l * HD, beta + (size_t)l * HD,
                                          scale, shift);
    res_mfma_kernel<<<ntiles, 512, 0, stream>>>(xb, aggb, Wsm, bs, scale, shift,
                                                out, l == NL - 1 ? 1 : 0);
  }
}

// Round 10
// 368.540 us; speedup vs baseline: 15.2246x; 1.2129x over previous
//
#include <hip/hip_runtime.h>
#include <hip/hip_bf16.h>
#include <stdint.h>

#define NN 50000
#define NE 800000
#define HD 128
#define NL 3
#define EPS_BN 1e-5f
#define EPS_NORM 1e-12f
#define NEG_SLOPE 0.1f

#define SCAN_CHUNK 256
#define SCAN_BLOCKS ((NN + SCAN_CHUNK - 1) / SCAN_CHUNK)   // 196
#define NTILES ((NN + 127) / 128)                          // 391

typedef __attribute__((ext_vector_type(8))) short bf16x8;
typedef __attribute__((ext_vector_type(4))) float f32x4;

static __device__ __forceinline__ unsigned pack_bf16(float a, float b) {
  unsigned ua = __builtin_bit_cast(unsigned, a);
  unsigned ub = __builtin_bit_cast(unsigned, b);
  ua = (ua + 0x7fffu + ((ua >> 16) & 1u)) >> 16;   // RNE
  ub = (ub + 0x7fffu + ((ub >> 16) & 1u)) >> 16;
  return ua | (ub << 16);
}
static __device__ __forceinline__ ushort bf16of(float f) {
  unsigned u = __builtin_bit_cast(unsigned, f);
  u = (u + 0x7fffu + ((u >> 16) & 1u)) >> 16;
  return (ushort)u;
}
static __device__ __forceinline__ float bflo(unsigned u) { return __builtin_bit_cast(float, u << 16); }
static __device__ __forceinline__ float bfhi(unsigned u) { return __builtin_bit_cast(float, u & 0xffff0000u); }

// ---------------- CSR build ----------------
__global__ __launch_bounds__(256) void hist_kernel(const int* __restrict__ dst, int* __restrict__ degi) {
  int i = blockIdx.x * 256 + threadIdx.x;
  if (i < NE) atomicAdd(&degi[dst[i]], 1);
}

__global__ __launch_bounds__(256) void blocksum_kernel(const int* __restrict__ degi,
                                                       int* __restrict__ blocksum) {
  __shared__ int sh[256];
  int t = threadIdx.x;
  int i = blockIdx.x * 256 + t;
  sh[t] = (i < NN) ? degi[i] : 0;
  __syncthreads();
  for (int off = 128; off >= 1; off >>= 1) {
    if (t < off) sh[t] += sh[t + off];
    __syncthreads();
  }
  if (t == 0) blocksum[blockIdx.x] = sh[0];
}

__global__ __launch_bounds__(256) void blockscan_kernel(int* __restrict__ blocksum,
                                                        int* __restrict__ blockoff,
                                                        int* __restrict__ rowptr) {
  __shared__ int sh[256];
  int t = threadIdx.x;
  int v = (t < SCAN_BLOCKS) ? blocksum[t] : 0;
  sh[t] = v;
  __syncthreads();
  for (int off = 1; off < 256; off <<= 1) {
    int u = (t >= off) ? sh[t - off] : 0;
    __syncthreads();
    sh[t] += u;
    __syncthreads();
  }
  if (t < SCAN_BLOCKS) blockoff[t] = sh[t] - v;
  if (t == 255) rowptr[NN] = sh[255];
}

__global__ __launch_bounds__(256) void chunkscan_kernel(const int* __restrict__ degi,
                                                        const int* __restrict__ blockoff,
                                                        int* __restrict__ rowptr,
                                                        int* __restrict__ cursor,
                                                        float* __restrict__ invdeg) {
  __shared__ int sh[256];
  int t = threadIdx.x;
  int i = blockIdx.x * 256 + t;
  int d = (i < NN) ? degi[i] : 0;
  sh[t] = d;
  __syncthreads();
  for (int off = 1; off < 256; off <<= 1) {
    int u = (t >= off) ? sh[t - off] : 0;
    __syncthreads();
    sh[t] += u;
    __syncthreads();
  }
  if (i < NN) {
    int pre = blockoff[blockIdx.x] + sh[t] - d;
    rowptr[i] = pre;
    cursor[i] = pre;
    invdeg[i] = 1.0f / fmaxf((float)d, 1.0f);
  }
}

__global__ __launch_bounds__(256) void fill_kernel(const int* __restrict__ src,
                                                   const int* __restrict__ dst,
                                                   int* __restrict__ cursor,
                                                   int* __restrict__ esrc) {
  int e = blockIdx.x * 256 + threadIdx.x;
  if (e < NE) {
    int pos = atomicAdd(&cursor[dst[e]], 1);
    esrc[pos] = src[e];
  }
}

// ---------------- f32 -> bf16 convert ----------------
__global__ __launch_bounds__(256) void tobf16_kernel(const float* __restrict__ x, ushort* __restrict__ xb) {
  int i = blockIdx.x * 256 + threadIdx.x;
  if (i < NN * 64) {
    float2 f = *(const float2*)(x + (size_t)i * 2);
    *(unsigned*)(xb + (size_t)i * 2) = pack_bf16(f.x, f.y);
  }
}

// ---------------- one-time weight pre-pack (swizzled bf16 LDS images) ----------------
__global__ __launch_bounds__(256) void packL_kernel(const float* __restrict__ Wl,
                                                    const float* __restrict__ Wr,
                                                    unsigned* __restrict__ wpackL) {
  int i = blockIdx.x * 256 + threadIdx.x;
  if (i >= NL * 16384) return;
  int l = i >> 14, rem = i & 16383;
  int c = rem >> 7, kp = rem & 127;
  int k2 = kp * 2;
  float f0, f1;
  if (k2 < HD) { const float* W = Wl + (size_t)l * HD * HD + c * HD + k2; f0 = W[0]; f1 = W[1]; }
  else         { const float* W = Wr + (size_t)l * HD * HD + c * HD + (k2 - HD); f0 = W[0]; f1 = W[1]; }
  unsigned ba = (unsigned)(c * 512 + kp * 4) ^ (unsigned)((c & 7) << 4);
  *(unsigned*)((char*)(wpackL + (size_t)l * 16384) + ba) = pack_bf16(f0, f1);
}

__global__ __launch_bounds__(256) void packS_kernel(const float* __restrict__ Wsm,
                                                    unsigned* __restrict__ wpackS) {
  int i = blockIdx.x * 256 + threadIdx.x;
  if (i >= 8192) return;
  int c = i >> 6, kp = i & 63;
  int k2 = kp * 2;
  unsigned ba = (unsigned)(c * 256 + kp * 4) ^ (unsigned)((c & 7) << 4);
  *(unsigned*)((char*)wpackS + ba) = pack_bf16(Wsm[c * HD + k2], Wsm[c * HD + k2 + 1]);
}

// ---------------- gather-side aggregation (bf16 in/out, f32 accum) ----------------
__global__ __launch_bounds__(512) void agg_csr_kernel(const ushort* __restrict__ xb,
                                                      const int* __restrict__ rowptr,
                                                      const int* __restrict__ esrc,
                                                      const float* __restrict__ invdeg,
                                                      ushort* __restrict__ aggb) {
  int node = (blockIdx.x * 512 + threadIdx.x) >> 6;
  int lane = threadIdx.x & 63;
  if (node >= NN) return;
  int start = rowptr[node], end = rowptr[node + 1];
  float a0 = 0.f, a1 = 0.f;
  int e = start;
  for (; e + 4 <= end; e += 4) {
    int s0 = esrc[e], s1 = esrc[e + 1], s2 = esrc[e + 2], s3 = esrc[e + 3];
    unsigned u0 = *(const unsigned*)(xb + (size_t)s0 * HD + lane * 2);
    unsigned u1 = *(const unsigned*)(xb + (size_t)s1 * HD + lane * 2);
    unsigned u2 = *(const unsigned*)(xb + (size_t)s2 * HD + lane * 2);
    unsigned u3 = *(const unsigned*)(xb + (size_t)s3 * HD + lane * 2);
    a0 += (bflo(u0) + bflo(u1)) + (bflo(u2) + bflo(u3));
    a1 += (bfhi(u0) + bfhi(u1)) + (bfhi(u2) + bfhi(u3));
  }
  for (; e < end; ++e) {
    unsigned u = *(const unsigned*)(xb + (size_t)esrc[e] * HD + lane * 2);
    a0 += bflo(u);
    a1 += bfhi(u);
  }
  float id = invdeg[node];
  *(unsigned*)(aggb + (size_t)node * HD + lane * 2) = pack_bf16(a0 * id, a1 * id);
}

// ---------------- MFMA: pre = L2norm([aggb|xb] @ [Wl|Wr]^T + bl), BN stats ----------------
// B pre-packed swizzled image -> straight 64 KB LDS copy. A in registers.
// pre written in fragment-native layout: prebn[(bid*32 + wave*4 + r)*64 + lane] = uint4 (8 bf16).
__global__ __launch_bounds__(512, 4) void mfma_pre_kernel(
    const ushort* __restrict__ aggb, const ushort* __restrict__ xb,
    const unsigned* __restrict__ wpackL, const float* __restrict__ bl,
    uint4* __restrict__ prebn,
    float* __restrict__ colsum, float* __restrict__ colsumsq) {
  __shared__ unsigned Bsw[16384];   // 64 KB
  __shared__ float lsum[HD], lsq[HD];
  const int tid = threadIdx.x;
  {
    const uint4* s = (const uint4*)wpackL;
    uint4* d = (uint4*)Bsw;
#pragma unroll
    for (int i = 0; i < 8; ++i) d[tid + i * 512] = s[tid + i * 512];
  }
  if (tid < HD) { lsum[tid] = 0.f; lsq[tid] = 0.f; }

  const int wave = tid >> 6, lane = tid & 63;
  const int lhi = lane >> 4, llo = lane & 15;
  int arow = blockIdx.x * 128 + wave * 16 + llo;
  if (arow >= NN) arow = NN - 1;
  const size_t rb = (size_t)arow * 256;  // row byte stride = 128 bf16

  uint4 areg[8];
#pragma unroll
  for (int ks = 0; ks < 4; ++ks) {
    areg[ks]     = *(const uint4*)((const char*)aggb + rb + ks * 64 + lhi * 16);
    areg[ks + 4] = *(const uint4*)((const char*)xb   + rb + ks * 64 + lhi * 16);
  }

  f32x4 acc[8];
#pragma unroll
  for (int ct = 0; ct < 8; ++ct) {
    float b = bl[ct * 16 + llo];
    acc[ct] = (f32x4){b, b, b, b};
  }
  __syncthreads();

#pragma unroll
  for (int ks = 0; ks < 8; ++ks) {
    bf16x8 a = __builtin_bit_cast(bf16x8, areg[ks]);
#pragma unroll
    for (int ct = 0; ct < 8; ++ct) {
      int bcol = ct * 16 + llo;
      unsigned bb = (unsigned)(bcol * 512 + ks * 64 + lhi * 16) ^ (unsigned)((bcol & 7) << 4);
      bf16x8 b = *(const bf16x8*)((const char*)Bsw + bb);
      acc[ct] = __builtin_amdgcn_mfma_f32_16x16x32_bf16(a, b, acc[ct], 0, 0, 0);
    }
  }

  float cs[8] = {0, 0, 0, 0, 0, 0, 0, 0}, cq[8] = {0, 0, 0, 0, 0, 0, 0, 0};
#pragma unroll
  for (int r = 0; r < 4; ++r) {
    int orow = blockIdx.x * 128 + wave * 16 + lhi * 4 + r;
    float p[8];
    float ss = 0.f;
#pragma unroll
    for (int ct = 0; ct < 8; ++ct) { p[ct] = acc[ct][r]; ss += p[ct] * p[ct]; }
#pragma unroll
    for (int m = 8; m >= 1; m >>= 1) ss += __shfl_xor(ss, m, 64);
    float inv = 1.0f / fmaxf(sqrtf(ss), EPS_NORM);
#pragma unroll
    for (int ct = 0; ct < 8; ++ct) p[ct] *= inv;
    uint4 o;
    o.x = pack_bf16(p[0], p[1]);
    o.y = pack_bf16(p[2], p[3]);
    o.z = pack_bf16(p[4], p[5]);
    o.w = pack_bf16(p[6], p[7]);
    prebn[((size_t)blockIdx.x * 32 + wave * 4 + r) * 64 + lane] = o;
    if (orow < NN) {
#pragma unroll
      for (int ct = 0; ct < 8; ++ct) { cs[ct] += p[ct]; cq[ct] += p[ct] * p[ct]; }
    }
  }
#pragma unroll
  for (int ct = 0; ct < 8; ++ct) {
    atomicAdd(&lsum[ct * 16 + llo], cs[ct]);
    atomicAdd(&lsq[ct * 16 + llo], cq[ct]);
  }
  __syncthreads();
  if (tid < HD) {
    atomicAdd(&colsum[tid], lsum[tid]);
    atomicAdd(&colsumsq[tid], lsq[tid]);
  }
}

// ---------------- finalize BN stats ----------------
__global__ __launch_bounds__(HD) void finalize_kernel(
    const float* __restrict__ colsum, const float* __restrict__ colsumsq,
    const float* __restrict__ gamma, const float* __restrict__ beta,
    float* __restrict__ scale, float* __restrict__ shift) {
  int f = threadIdx.x;
  float mu = colsum[f] * (1.0f / NN);
  float ex2 = colsumsq[f] * (1.0f / NN);
  float var = ex2 - mu * mu;
  float sc = gamma[f] * rsqrtf(var + EPS_BN);
  scale[f] = sc;
  shift[f] = beta[f] - mu * sc;
}

// ---------------- MFMA: out = lrelu(BN(pre)) + xb@Ws^T + bs ----------------
__global__ __launch_bounds__(512, 4) void res_mfma_kernel(
    ushort* __restrict__ xb, const uint4* __restrict__ prebn,
    const unsigned* __restrict__ wpackS, const float* __restrict__ bs,
    const float* __restrict__ scale, const float* __restrict__ shift,
    float* __restrict__ outf, int last) {
  __shared__ unsigned Bsw[8192];   // 32 KB
  const int tid = threadIdx.x;
  {
    const uint4* s = (const uint4*)wpackS;
    uint4* d = (uint4*)Bsw;
#pragma unroll
    for (int i = 0; i < 4; ++i) d[tid + i * 512] = s[tid + i * 512];
  }
  const int wave = tid >> 6, lane = tid & 63;
  const int lhi = lane >> 4, llo = lane & 15;
  int arow = blockIdx.x * 128 + wave * 16 + llo;
  if (arow >= NN) arow = NN - 1;
  const size_t rb = (size_t)arow * 256;

  uint4 areg[4];
#pragma unroll
  for (int ks = 0; ks < 4; ++ks)
    areg[ks] = *(const uint4*)((const char*)xb + rb + ks * 64 + lhi * 16);
  uint4 pv4[4];
#pragma unroll
  for (int r = 0; r < 4; ++r)
    pv4[r] = prebn[((size_t)blockIdx.x * 32 + wave * 4 + r) * 64 + lane];

  f32x4 acc[8];
  float sc[8], sh[8];
#pragma unroll
  for (int ct = 0; ct < 8; ++ct) {
    int C = ct * 16 + llo;
    float b = bs[C];
    acc[ct] = (f32x4){b, b, b, b};
    sc[ct] = scale[C];
    sh[ct] = shift[C];
  }
  __syncthreads();

#pragma unroll
  for (int ks = 0; ks < 4; ++ks) {
    bf16x8 a = __builtin_bit_cast(bf16x8, areg[ks]);
#pragma unroll
    for (int ct = 0; ct < 8; ++ct) {
      int bcol = ct * 16 + llo;
      unsigned bb = (unsigned)(bcol * 256 + ks * 64 + lhi * 16) ^ (unsigned)((bcol & 7) << 4);
      bf16x8 b = *(const bf16x8*)((const char*)Bsw + bb);
      acc[ct] = __builtin_amdgcn_mfma_f32_16x16x32_bf16(a, b, acc[ct], 0, 0, 0);
    }
  }

#pragma unroll
  for (int r = 0; r < 4; ++r) {
    int orow = blockIdx.x * 128 + wave * 16 + lhi * 4 + r;
    if (orow < NN) {
      const unsigned* pw = (const unsigned*)&pv4[r];
#pragma unroll
      for (int ct = 0; ct < 8; ++ct) {
        unsigned w = pw[ct >> 1];
        float pv = (ct & 1) ? bfhi(w) : bflo(w);
        float v = pv * sc[ct] + sh[ct];
        v = v >= 0.f ? v : NEG_SLOPE * v;
        float o = v + acc[ct][r];
        if (last) outf[(size_t)orow * HD + ct * 16 + llo] = o;
        else      xb[(size_t)orow * HD + ct * 16 + llo] = bf16of(o);
      }
    }
  }
}

extern "C" void kernel_launch(void* const* d_in, const int* in_sizes, int n_in,
                              void* d_out, int out_size, void* d_ws, size_t ws_size,
                              hipStream_t stream) {
  const float* x0    = (const float*)d_in[0];
  const int*   ei    = (const int*)d_in[1];
  const float* Wl    = (const float*)d_in[2];
  const float* bl    = (const float*)d_in[3];
  const float* Wr    = (const float*)d_in[4];
  const float* gamma = (const float*)d_in[5];
  const float* beta  = (const float*)d_in[6];
  const float* Wsm   = (const float*)d_in[7];
  const float* bs    = (const float*)d_in[8];
  float* out = (float*)d_out;

  char* w = (char*)d_ws;
  ushort* aggb = (ushort*)w;        w += (size_t)NN * HD * 2;            // 12.8 MB
  ushort* xb   = (ushort*)w;        w += (size_t)NN * HD * 2;            // 12.8 MB
  uint4* prebn = (uint4*)w;         w += (size_t)NTILES * 32 * 64 * 16;  // 12.81 MB
  unsigned* wpackL = (unsigned*)w;  w += (size_t)NL * 16384 * 4;         // 192 KB
  unsigned* wpackS = (unsigned*)w;  w += 8192 * 4;                       // 32 KB
  float* invdeg = (float*)w;        w += (size_t)NN * 4;
  float* colsum = (float*)w;        w += HD * 4;
  float* colsumsq = (float*)w;      w += HD * 4;
  float* scale = (float*)w;         w += HD * 4;
  float* shift = (float*)w;         w += HD * 4;
  int* degi = (int*)w;              w += (size_t)NN * 4;
  int* rowptr = (int*)w;            w += (size_t)(NN + 1) * 4;
  int* cursor = (int*)w;            w += (size_t)NN * 4;
  int* blocksum = (int*)w;          w += SCAN_BLOCKS * 4;
  int* blockoff = (int*)w;          w += SCAN_BLOCKS * 4;
  int* esrc = (int*)w;              w += (size_t)NE * 4;

  const int* src = ei;
  const int* dst = ei + NE;

  // one-time: CSR build + bf16 convert + weight pre-pack
  hipMemsetAsync(degi, 0, NN * sizeof(int), stream);
  hist_kernel<<<(NE + 255) / 256, 256, 0, stream>>>(dst, degi);
  blocksum_kernel<<<SCAN_BLOCKS, 256, 0, stream>>>(degi, blocksum);
  blockscan_kernel<<<1, 256, 0, stream>>>(blocksum, blockoff, rowptr);
  chunkscan_kernel<<<SCAN_BLOCKS, 256, 0, stream>>>(degi, blockoff, rowptr, cursor, invdeg);
  fill_kernel<<<(NE + 255) / 256, 256, 0, stream>>>(src, dst, cursor, esrc);
  tobf16_kernel<<<(NN * 64 + 255) / 256, 256, 0, stream>>>(x0, xb);
  packL_kernel<<<(NL * 16384 + 255) / 256, 256, 0, stream>>>(Wl, Wr, wpackL);
  packS_kernel<<<32, 256, 0, stream>>>(Wsm, wpackS);

  for (int l = 0; l < NL; ++l) {
    hipMemsetAsync(colsum, 0, 2 * HD * sizeof(float), stream);
    agg_csr_kernel<<<(NN * 64 + 511) / 512, 512, 0, stream>>>(xb, rowptr, esrc, invdeg, aggb);
    mfma_pre_kernel<<<NTILES, 512, 0, stream>>>(aggb, xb, wpackL + (size_t)l * 16384,
                                                bl + (size_t)l * HD, prebn, colsum, colsumsq);
    finalize_kernel<<<1, HD, 0, stream>>>(colsum, colsumsq,
                                          gamma + (size_t)l * HD, beta + (size_t)l * HD,
                                          scale, shift);
    res_mfma_kernel<<<NTILES, 512, 0, stream>>>(xb, prebn, wpackS, bs, scale, shift,
                                                out, l == NL - 1 ? 1 : 0);
  }
}

// Round 12
// 352.016 us; speedup vs baseline: 15.9393x; 1.0469x over previous
//
#include <hip/hip_runtime.h>
#include <hip/hip_bf16.h>
#include <stdint.h>

#define NN 50000
#define NE 800000
#define HD 128
#define NL 3
#define EPS_BN 1e-5f
#define EPS_NORM 1e-12f
#define NEG_SLOPE 0.1f

#define SCAN_CHUNK 256
#define SCAN_BLOCKS ((NN + SCAN_CHUNK - 1) / SCAN_CHUNK)   // 196
#define NTILES ((NN + 127) / 128)                          // 391

typedef __attribute__((ext_vector_type(8))) short bf16x8;
typedef __attribute__((ext_vector_type(4))) float f32x4;

static __device__ __forceinline__ unsigned pack_bf16(float a, float b) {
  unsigned ua = __builtin_bit_cast(unsigned, a);
  unsigned ub = __builtin_bit_cast(unsigned, b);
  ua = (ua + 0x7fffu + ((ua >> 16) & 1u)) >> 16;   // RNE
  ub = (ub + 0x7fffu + ((ub >> 16) & 1u)) >> 16;
  return ua | (ub << 16);
}
static __device__ __forceinline__ ushort bf16of(float f) {
  unsigned u = __builtin_bit_cast(unsigned, f);
  u = (u + 0x7fffu + ((u >> 16) & 1u)) >> 16;
  return (ushort)u;
}
static __device__ __forceinline__ float bflo(unsigned u) { return __builtin_bit_cast(float, u << 16); }
static __device__ __forceinline__ float bfhi(unsigned u) { return __builtin_bit_cast(float, u & 0xffff0000u); }

// ---------------- CSR build ----------------
__global__ __launch_bounds__(256) void hist_kernel(const int* __restrict__ dst, int* __restrict__ degi) {
  int i = blockIdx.x * 256 + threadIdx.x;
  if (i < NE) atomicAdd(&degi[dst[i]], 1);
}

__global__ __launch_bounds__(256) void blocksum_kernel(const int* __restrict__ degi,
                                                       int* __restrict__ blocksum) {
  __shared__ int sh[256];
  int t = threadIdx.x;
  int i = blockIdx.x * 256 + t;
  sh[t] = (i < NN) ? degi[i] : 0;
  __syncthreads();
  for (int off = 128; off >= 1; off >>= 1) {
    if (t < off) sh[t] += sh[t + off];
    __syncthreads();
  }
  if (t == 0) blocksum[blockIdx.x] = sh[0];
}

__global__ __launch_bounds__(256) void blockscan_kernel(int* __restrict__ blocksum,
                                                        int* __restrict__ blockoff,
                                                        int* __restrict__ rowptr) {
  __shared__ int sh[256];
  int t = threadIdx.x;
  int v = (t < SCAN_BLOCKS) ? blocksum[t] : 0;
  sh[t] = v;
  __syncthreads();
  for (int off = 1; off < 256; off <<= 1) {
    int u = (t >= off) ? sh[t - off] : 0;
    __syncthreads();
    sh[t] += u;
    __syncthreads();
  }
  if (t < SCAN_BLOCKS) blockoff[t] = sh[t] - v;
  if (t == 255) rowptr[NN] = sh[255];
}

__global__ __launch_bounds__(256) void chunkscan_kernel(const int* __restrict__ degi,
                                                        const int* __restrict__ blockoff,
                                                        int* __restrict__ rowptr,
                                                        int* __restrict__ cursor,
                                                        float* __restrict__ invdeg) {
  __shared__ int sh[256];
  int t = threadIdx.x;
  int i = blockIdx.x * 256 + t;
  int d = (i < NN) ? degi[i] : 0;
  sh[t] = d;
  __syncthreads();
  for (int off = 1; off < 256; off <<= 1) {
    int u = (t >= off) ? sh[t - off] : 0;
    __syncthreads();
    sh[t] += u;
    __syncthreads();
  }
  if (i < NN) {
    int pre = blockoff[blockIdx.x] + sh[t] - d;
    rowptr[i] = pre;
    cursor[i] = pre;
    invdeg[i] = 1.0f / fmaxf((float)d, 1.0f);
  }
}

__global__ __launch_bounds__(256) void fill_kernel(const int* __restrict__ src,
                                                   const int* __restrict__ dst,
                                                   int* __restrict__ cursor,
                                                   int* __restrict__ esrc) {
  int e = blockIdx.x * 256 + threadIdx.x;
  if (e < NE) {
    int pos = atomicAdd(&cursor[dst[e]], 1);
    esrc[pos] = src[e];
  }
}

// ---------------- f32 -> bf16 convert ----------------
__global__ __launch_bounds__(256) void tobf16_kernel(const float* __restrict__ x, ushort* __restrict__ xb) {
  int i = blockIdx.x * 256 + threadIdx.x;
  if (i < NN * 64) {
    float2 f = *(const float2*)(x + (size_t)i * 2);
    *(unsigned*)(xb + (size_t)i * 2) = pack_bf16(f.x, f.y);
  }
}

// ---------------- one-time weight pre-pack (swizzled bf16 LDS images) ----------------
__global__ __launch_bounds__(256) void packW_kernel(const float* __restrict__ Wl,
                                                    const float* __restrict__ Wr,
                                                    const float* __restrict__ Wsm,
                                                    unsigned* __restrict__ wpackL,
                                                    unsigned* __restrict__ wpackS) {
  int i = blockIdx.x * 256 + threadIdx.x;
  if (i < NL * 16384) {
    int l = i >> 14, rem = i & 16383;
    int c = rem >> 7, kp = rem & 127;
    int k2 = kp * 2;
    float f0, f1;
    if (k2 < HD) { const float* W = Wl + (size_t)l * HD * HD + c * HD + k2; f0 = W[0]; f1 = W[1]; }
    else         { const float* W = Wr + (size_t)l * HD * HD + c * HD + (k2 - HD); f0 = W[0]; f1 = W[1]; }
    unsigned ba = (unsigned)(c * 512 + kp * 4) ^ (unsigned)((c & 7) << 4);
    *(unsigned*)((char*)(wpackL + (size_t)l * 16384) + ba) = pack_bf16(f0, f1);
  } else if (i < NL * 16384 + 8192) {
    int j = i - NL * 16384;
    int c = j >> 6, kp = j & 63;
    int k2 = kp * 2;
    unsigned ba = (unsigned)(c * 256 + kp * 4) ^ (unsigned)((c & 7) << 4);
    *(unsigned*)((char*)wpackS + ba) = pack_bf16(Wsm[c * HD + k2], Wsm[c * HD + k2 + 1]);
  }
}

// ---------------- gather-side aggregation v2: 2 nodes per wave, uint2 loads ----------------
__global__ __launch_bounds__(512) void agg_csr_kernel(const ushort* __restrict__ xb,
                                                      const int* __restrict__ rowptr,
                                                      const int* __restrict__ esrc,
                                                      const float* __restrict__ invdeg,
                                                      ushort* __restrict__ aggb) {
  int wid = (blockIdx.x * 512 + threadIdx.x) >> 6;
  int lane = threadIdx.x & 63;
  int half = lane >> 5, sub = lane & 31;
  int node = wid * 2 + half;
  if (node >= NN) return;
  int start = rowptr[node], end = rowptr[node + 1];
  float a0 = 0.f, a1 = 0.f, a2 = 0.f, a3 = 0.f;
  int e = start;
  for (; e + 4 <= end; e += 4) {
    int s0 = esrc[e], s1 = esrc[e + 1], s2 = esrc[e + 2], s3 = esrc[e + 3];
    uint2 u0 = *(const uint2*)((const char*)xb + (size_t)s0 * 256 + sub * 8);
    uint2 u1 = *(const uint2*)((const char*)xb + (size_t)s1 * 256 + sub * 8);
    uint2 u2 = *(const uint2*)((const char*)xb + (size_t)s2 * 256 + sub * 8);
    uint2 u3 = *(const uint2*)((const char*)xb + (size_t)s3 * 256 + sub * 8);
    a0 += (bflo(u0.x) + bflo(u1.x)) + (bflo(u2.x) + bflo(u3.x));
    a1 += (bfhi(u0.x) + bfhi(u1.x)) + (bfhi(u2.x) + bfhi(u3.x));
    a2 += (bflo(u0.y) + bflo(u1.y)) + (bflo(u2.y) + bflo(u3.y));
    a3 += (bfhi(u0.y) + bfhi(u1.y)) + (bfhi(u2.y) + bfhi(u3.y));
  }
  for (; e < end; ++e) {
    uint2 u = *(const uint2*)((const char*)xb + (size_t)esrc[e] * 256 + sub * 8);
    a0 += bflo(u.x);
    a1 += bfhi(u.x);
    a2 += bflo(u.y);
    a3 += bfhi(u.y);
  }
  float id = invdeg[node];
  uint2 o;
  o.x = pack_bf16(a0 * id, a1 * id);
  o.y = pack_bf16(a2 * id, a3 * id);
  *(uint2*)((char*)aggb + (size_t)node * 256 + sub * 8) = o;
}

// ---------------- MFMA: pre = L2norm([aggb|xb] @ [Wl|Wr]^T + bl), BN stats ----------------
__global__ __launch_bounds__(512, 4) void mfma_pre_kernel(
    const ushort* __restrict__ aggb, const ushort* __restrict__ xb,
    const unsigned* __restrict__ wpackL, const float* __restrict__ bl,
    uint4* __restrict__ prebn,
    float* __restrict__ colsum, float* __restrict__ colsumsq) {
  __shared__ unsigned Bsw[16384];   // 64 KB
  __shared__ float lsum[HD], lsq[HD];
  const int tid = threadIdx.x;
  {
    const uint4* s = (const uint4*)wpackL;
    uint4* d = (uint4*)Bsw;
#pragma unroll
    for (int i = 0; i < 8; ++i) d[tid + i * 512] = s[tid + i * 512];
  }
  if (tid < HD) { lsum[tid] = 0.f; lsq[tid] = 0.f; }

  const int wave = tid >> 6, lane = tid & 63;
  const int lhi = lane >> 4, llo = lane & 15;
  int arow = blockIdx.x * 128 + wave * 16 + llo;
  if (arow >= NN) arow = NN - 1;
  const size_t rb = (size_t)arow * 256;

  uint4 areg[8];
#pragma unroll
  for (int ks = 0; ks < 4; ++ks) {
    areg[ks]     = *(const uint4*)((const char*)aggb + rb + ks * 64 + lhi * 16);
    areg[ks + 4] = *(const uint4*)((const char*)xb   + rb + ks * 64 + lhi * 16);
  }

  f32x4 acc[8];
#pragma unroll
  for (int ct = 0; ct < 8; ++ct) {
    float b = bl[ct * 16 + llo];
    acc[ct] = (f32x4){b, b, b, b};
  }
  __syncthreads();

#pragma unroll
  for (int ks = 0; ks < 8; ++ks) {
    bf16x8 a = __builtin_bit_cast(bf16x8, areg[ks]);
#pragma unroll
    for (int ct = 0; ct < 8; ++ct) {
      int bcol = ct * 16 + llo;
      unsigned bb = (unsigned)(bcol * 512 + ks * 64 + lhi * 16) ^ (unsigned)((bcol & 7) << 4);
      bf16x8 b = *(const bf16x8*)((const char*)Bsw + bb);
      acc[ct] = __builtin_amdgcn_mfma_f32_16x16x32_bf16(a, b, acc[ct], 0, 0, 0);
    }
  }

  float cs[8] = {0, 0, 0, 0, 0, 0, 0, 0}, cq[8] = {0, 0, 0, 0, 0, 0, 0, 0};
#pragma unroll
  for (int r = 0; r < 4; ++r) {
    int orow = blockIdx.x * 128 + wave * 16 + lhi * 4 + r;
    float p[8];
    float ss = 0.f;
#pragma unroll
    for (int ct = 0; ct < 8; ++ct) { p[ct] = acc[ct][r]; ss += p[ct] * p[ct]; }
#pragma unroll
    for (int m = 8; m >= 1; m >>= 1) ss += __shfl_xor(ss, m, 64);
    float inv = 1.0f / fmaxf(sqrtf(ss), EPS_NORM);
#pragma unroll
    for (int ct = 0; ct < 8; ++ct) p[ct] *= inv;
    uint4 o;
    o.x = pack_bf16(p[0], p[1]);
    o.y = pack_bf16(p[2], p[3]);
    o.z = pack_bf16(p[4], p[5]);
    o.w = pack_bf16(p[6], p[7]);
    prebn[((size_t)blockIdx.x * 32 + wave * 4 + r) * 64 + lane] = o;
    if (orow < NN) {
#pragma unroll
      for (int ct = 0; ct < 8; ++ct) { cs[ct] += p[ct]; cq[ct] += p[ct] * p[ct]; }
    }
  }
#pragma unroll
  for (int ct = 0; ct < 8; ++ct) {
    atomicAdd(&lsum[ct * 16 + llo], cs[ct]);
    atomicAdd(&lsq[ct * 16 + llo], cq[ct]);
  }
  __syncthreads();
  if (tid < HD) {
    atomicAdd(&colsum[tid], lsum[tid]);
    atomicAdd(&colsumsq[tid], lsq[tid]);
  }
}

// ---------------- finalize BN stats ----------------
__global__ __launch_bounds__(HD) void finalize_kernel(
    const float* __restrict__ colsum, const float* __restrict__ colsumsq,
    const float* __restrict__ gamma, const float* __restrict__ beta,
    float* __restrict__ scale, float* __restrict__ shift) {
  int f = threadIdx.x;
  float mu = colsum[f] * (1.0f / NN);
  float ex2 = colsumsq[f] * (1.0f / NN);
  float var = ex2 - mu * mu;
  float sc = gamma[f] * rsqrtf(var + EPS_BN);
  scale[f] = sc;
  shift[f] = beta[f] - mu * sc;
}

// ---------------- MFMA: out = lrelu(BN(pre)) + xb@Ws^T + bs ----------------
__global__ __launch_bounds__(512, 4) void res_mfma_kernel(
    ushort* __restrict__ xb, const uint4* __restrict__ prebn,
    const unsigned* __restrict__ wpackS, const float* __restrict__ bs,
    const float* __restrict__ scale, const float* __restrict__ shift,
    float* __restrict__ outf, int last) {
  __shared__ unsigned Bsw[8192];   // 32 KB
  const int tid = threadIdx.x;
  {
    const uint4* s = (const uint4*)wpackS;
    uint4* d = (uint4*)Bsw;
#pragma unroll
    for (int i = 0; i < 4; ++i) d[tid + i * 512] = s[tid + i * 512];
  }
  const int wave = tid >> 6, lane = tid & 63;
  const int lhi = lane >> 4, llo = lane & 15;
  int arow = blockIdx.x * 128 + wave * 16 + llo;
  if (arow >= NN) arow = NN - 1;
  const size_t rb = (size_t)arow * 256;

  uint4 areg[4];
#pragma unroll
  for (int ks = 0; ks < 4; ++ks)
    areg[ks] = *(const uint4*)((const char*)xb + rb + ks * 64 + lhi * 16);
  uint4 pv4[4];
#pragma unroll
  for (int r = 0; r < 4; ++r)
    pv4[r] = prebn[((size_t)blockIdx.x * 32 + wave * 4 + r) * 64 + lane];

  f32x4 acc[8];
  float sc[8], sh[8];
#pragma unroll
  for (int ct = 0; ct < 8; ++ct) {
    int C = ct * 16 + llo;
    float b = bs[C];
    acc[ct] = (f32x4){b, b, b, b};
    sc[ct] = scale[C];
    sh[ct] = shift[C];
  }
  __syncthreads();

#pragma unroll
  for (int ks = 0; ks < 4; ++ks) {
    bf16x8 a = __builtin_bit_cast(bf16x8, areg[ks]);
#pragma unroll
    for (int ct = 0; ct < 8; ++ct) {
      int bcol = ct * 16 + llo;
      unsigned bb = (unsigned)(bcol * 256 + ks * 64 + lhi * 16) ^ (unsigned)((bcol & 7) << 4);
      bf16x8 b = *(const bf16x8*)((const char*)Bsw + bb);
      acc[ct] = __builtin_amdgcn_mfma_f32_16x16x32_bf16(a, b, acc[ct], 0, 0, 0);
    }
  }

#pragma unroll
  for (int r = 0; r < 4; ++r) {
    int orow = blockIdx.x * 128 + wave * 16 + lhi * 4 + r;
    if (orow < NN) {
      const unsigned* pw = (const unsigned*)&pv4[r];
#pragma unroll
      for (int ct = 0; ct < 8; ++ct) {
        unsigned w = pw[ct >> 1];
        float pv = (ct & 1) ? bfhi(w) : bflo(w);
        float v = pv * sc[ct] + sh[ct];
        v = v >= 0.f ? v : NEG_SLOPE * v;
        float o = v + acc[ct][r];
        if (last) outf[(size_t)orow * HD + ct * 16 + llo] = o;
        else      xb[(size_t)orow * HD + ct * 16 + llo] = bf16of(o);
      }
    }
  }
}

extern "C" void kernel_launch(void* const* d_in, const int* in_sizes, int n_in,
                              void* d_out, int out_size, void* d_ws, size_t ws_size,
                              hipStream_t stream) {
  const float* x0    = (const float*)d_in[0];
  const int*   ei    = (const int*)d_in[1];
  const float* Wl    = (const float*)d_in[2];
  const float* bl    = (const float*)d_in[3];
  const float* Wr    = (const float*)d_in[4];
  const float* gamma = (const float*)d_in[5];
  const float* beta  = (const float*)d_in[6];
  const float* Wsm   = (const float*)d_in[7];
  const float* bs    = (const float*)d_in[8];
  float* out = (float*)d_out;

  char* w = (char*)d_ws;
  ushort* aggb = (ushort*)w;        w += (size_t)NN * HD * 2;            // 12.8 MB
  ushort* xb   = (ushort*)w;        w += (size_t)NN * HD * 2;            // 12.8 MB
  uint4* prebn = (uint4*)w;         w += (size_t)NTILES * 32 * 64 * 16;  // 12.81 MB
  unsigned* wpackL = (unsigned*)w;  w += (size_t)NL * 16384 * 4;         // 192 KB
  unsigned* wpackS = (unsigned*)w;  w += 8192 * 4;                       // 32 KB
  float* invdeg = (float*)w;        w += (size_t)NN * 4;
  float* colsum = (float*)w;        w += HD * 4;
  float* colsumsq = (float*)w;      w += HD * 4;
  float* scale = (float*)w;         w += HD * 4;
  float* shift = (float*)w;         w += HD * 4;
  int* degi = (int*)w;              w += (size_t)NN * 4;
  int* rowptr = (int*)w;            w += (size_t)(NN + 1) * 4;
  int* cursor = (int*)w;            w += (size_t)NN * 4;
  int* blocksum = (int*)w;          w += SCAN_BLOCKS * 4;
  int* blockoff = (int*)w;          w += SCAN_BLOCKS * 4;
  int* esrc = (int*)w;              w += (size_t)NE * 4;

  const int* srcp = ei;
  const int* dstp = ei + NE;

  // one-time: CSR build + bf16 convert + weight pre-pack
  hipMemsetAsync(degi, 0, NN * sizeof(int), stream);
  hist_kernel<<<(NE + 255) / 256, 256, 0, stream>>>(dstp, degi);
  blocksum_kernel<<<SCAN_BLOCKS, 256, 0, stream>>>(degi, blocksum);
  blockscan_kernel<<<1, 256, 0, stream>>>(blocksum, blockoff, rowptr);
  chunkscan_kernel<<<SCAN_BLOCKS, 256, 0, stream>>>(degi, blockoff, rowptr, cursor, invdeg);
  fill_kernel<<<(NE + 255) / 256, 256, 0, stream>>>(srcp, dstp, cursor, esrc);
  tobf16_kernel<<<(NN * 64 + 255) / 256, 256, 0, stream>>>(x0, xb);
  packW_kernel<<<(NL * 16384 + 8192 + 255) / 256, 256, 0, stream>>>(Wl, Wr, Wsm, wpackL, wpackS);

  const int aggBlocks = ((NN + 1) / 2 * 64 + 511) / 512;   // 2 nodes/wave
  for (int l = 0; l < NL; ++l) {
    hipMemsetAsync(colsum, 0, 2 * HD * sizeof(float), stream);
    agg_csr_kernel<<<aggBlocks, 512, 0, stream>>>(xb, rowptr, esrc, invdeg, aggb);
    mfma_pre_kernel<<<NTILES, 512, 0, stream>>>(aggb, xb, wpackL + (size_t)l * 16384,
                                                bl + (size_t)l * HD, prebn, colsum, colsumsq);
    finalize_kernel<<<1, HD, 0, stream>>>(colsum, colsumsq,
                                          gamma + (size_t)l * HD, beta + (size_t)l * HD,
                                          scale, shift);
    res_mfma_kernel<<<NTILES, 512, 0, stream>>>(xb, prebn, wpackS, bs, scale, shift,
                                                out, l == NL - 1 ? 1 : 0);
  }
}

// Round 14
// 341.010 us; speedup vs baseline: 16.4538x; 1.0323x over previous
//
#include <hip/hip_runtime.h>
#include <hip/hip_bf16.h>
#include <stdint.h>

#define NN 50000
#define NE 800000
#define HD 128
#define NL 3
#define EPS_BN 1e-5f
#define EPS_NORM 1e-12f
#define NEG_SLOPE 0.1f

#define SCAN_CHUNK 256
#define SCAN_BLOCKS ((NN + SCAN_CHUNK - 1) / SCAN_CHUNK)   // 196
#define NTILES ((NN + 127) / 128)                          // 391

typedef __attribute__((ext_vector_type(8))) short bf16x8;
typedef __attribute__((ext_vector_type(4))) float f32x4;

static __device__ __forceinline__ unsigned pack_bf16(float a, float b) {
  unsigned ua = __builtin_bit_cast(unsigned, a);
  unsigned ub = __builtin_bit_cast(unsigned, b);
  ua = (ua + 0x7fffu + ((ua >> 16) & 1u)) >> 16;   // RNE
  ub = (ub + 0x7fffu + ((ub >> 16) & 1u)) >> 16;
  return ua | (ub << 16);
}
static __device__ __forceinline__ ushort bf16of(float f) {
  unsigned u = __builtin_bit_cast(unsigned, f);
  u = (u + 0x7fffu + ((u >> 16) & 1u)) >> 16;
  return (ushort)u;
}
static __device__ __forceinline__ float bflo(unsigned u) { return __builtin_bit_cast(float, u << 16); }
static __device__ __forceinline__ float bfhi(unsigned u) { return __builtin_bit_cast(float, u & 0xffff0000u); }

// ---------------- CSR build ----------------
__global__ __launch_bounds__(256) void hist_kernel(const int* __restrict__ dst, int* __restrict__ degi) {
  int i = blockIdx.x * 256 + threadIdx.x;
  if (i < NE) atomicAdd(&degi[dst[i]], 1);
}

__global__ __launch_bounds__(256) void blocksum_kernel(const int* __restrict__ degi,
                                                       int* __restrict__ blocksum) {
  __shared__ int sh[256];
  int t = threadIdx.x;
  int i = blockIdx.x * 256 + t;
  sh[t] = (i < NN) ? degi[i] : 0;
  __syncthreads();
  for (int off = 128; off >= 1; off >>= 1) {
    if (t < off) sh[t] += sh[t + off];
    __syncthreads();
  }
  if (t == 0) blocksum[blockIdx.x] = sh[0];
}

__global__ __launch_bounds__(256) void blockscan_kernel(int* __restrict__ blocksum,
                                                        int* __restrict__ blockoff,
                                                        int* __restrict__ rowptr) {
  __shared__ int sh[256];
  int t = threadIdx.x;
  int v = (t < SCAN_BLOCKS) ? blocksum[t] : 0;
  sh[t] = v;
  __syncthreads();
  for (int off = 1; off < 256; off <<= 1) {
    int u = (t >= off) ? sh[t - off] : 0;
    __syncthreads();
    sh[t] += u;
    __syncthreads();
  }
  if (t < SCAN_BLOCKS) blockoff[t] = sh[t] - v;
  if (t == 255) rowptr[NN] = sh[255];
}

__global__ __launch_bounds__(256) void chunkscan_kernel(const int* __restrict__ degi,
                                                        const int* __restrict__ blockoff,
                                                        int* __restrict__ rowptr,
                                                        int* __restrict__ cursor,
                                                        float* __restrict__ invdeg) {
  __shared__ int sh[256];
  int t = threadIdx.x;
  int i = blockIdx.x * 256 + t;
  int d = (i < NN) ? degi[i] : 0;
  sh[t] = d;
  __syncthreads();
  for (int off = 1; off < 256; off <<= 1) {
    int u = (t >= off) ? sh[t - off] : 0;
    __syncthreads();
    sh[t] += u;
    __syncthreads();
  }
  if (i < NN) {
    int pre = blockoff[blockIdx.x] + sh[t] - d;
    rowptr[i] = pre;
    cursor[i] = pre;
    invdeg[i] = 1.0f / fmaxf((float)d, 1.0f);
  }
}

__global__ __launch_bounds__(256) void fill_kernel(const int* __restrict__ src,
                                                   const int* __restrict__ dst,
                                                   int* __restrict__ cursor,
                                                   int* __restrict__ esrc) {
  int e = blockIdx.x * 256 + threadIdx.x;
  if (e < NE) {
    int pos = atomicAdd(&cursor[dst[e]], 1);
    esrc[pos] = src[e];
  }
}

// ---------------- f32 -> bf16 convert ----------------
__global__ __launch_bounds__(256) void tobf16_kernel(const float* __restrict__ x, ushort* __restrict__ xb) {
  int i = blockIdx.x * 256 + threadIdx.x;
  if (i < NN * 64) {
    float2 f = *(const float2*)(x + (size_t)i * 2);
    *(unsigned*)(xb + (size_t)i * 2) = pack_bf16(f.x, f.y);
  }
}

// ---------------- one-time weight pre-pack (swizzled bf16 LDS images) ----------------
__global__ __launch_bounds__(256) void packW_kernel(const float* __restrict__ Wl,
                                                    const float* __restrict__ Wr,
                                                    const float* __restrict__ Wsm,
                                                    unsigned* __restrict__ wpackL,
                                                    unsigned* __restrict__ wpackS) {
  int i = blockIdx.x * 256 + threadIdx.x;
  if (i < NL * 16384) {
    int l = i >> 14, rem = i & 16383;
    int c = rem >> 7, kp = rem & 127;
    int k2 = kp * 2;
    float f0, f1;
    if (k2 < HD) { const float* W = Wl + (size_t)l * HD * HD + c * HD + k2; f0 = W[0]; f1 = W[1]; }
    else         { const float* W = Wr + (size_t)l * HD * HD + c * HD + (k2 - HD); f0 = W[0]; f1 = W[1]; }
    unsigned ba = (unsigned)(c * 512 + kp * 4) ^ (unsigned)((c & 7) << 4);
    *(unsigned*)((char*)(wpackL + (size_t)l * 16384) + ba) = pack_bf16(f0, f1);
  } else if (i < NL * 16384 + 8192) {
    int j = i - NL * 16384;
    int c = j >> 6, kp = j & 63;
    int k2 = kp * 2;
    unsigned ba = (unsigned)(c * 256 + kp * 4) ^ (unsigned)((c & 7) << 4);
    *(unsigned*)((char*)wpackS + ba) = pack_bf16(Wsm[c * HD + k2], Wsm[c * HD + k2 + 1]);
  }
}

// ---------------- gather-side aggregation v2: 2 nodes per wave, uint2 loads ----------------
// Block 0 also zeroes the BN stat accumulators (replaces a memset dispatch).
__global__ __launch_bounds__(512) void agg_csr_kernel(const ushort* __restrict__ xb,
                                                      const int* __restrict__ rowptr,
                                                      const int* __restrict__ esrc,
                                                      const float* __restrict__ invdeg,
                                                      ushort* __restrict__ aggb,
                                                      float* __restrict__ colsum,
                                                      float* __restrict__ colsumsq) {
  if (blockIdx.x == 0 && threadIdx.x < 2 * HD) {
    if (threadIdx.x < HD) colsum[threadIdx.x] = 0.f;
    else colsumsq[threadIdx.x - HD] = 0.f;
  }
  int wid = (blockIdx.x * 512 + threadIdx.x) >> 6;
  int lane = threadIdx.x & 63;
  int half = lane >> 5, sub = lane & 31;
  int node = wid * 2 + half;
  if (node >= NN) return;
  int start = rowptr[node], end = rowptr[node + 1];
  float a0 = 0.f, a1 = 0.f, a2 = 0.f, a3 = 0.f;
  int e = start;
  for (; e + 4 <= end; e += 4) {
    int s0 = esrc[e], s1 = esrc[e + 1], s2 = esrc[e + 2], s3 = esrc[e + 3];
    uint2 u0 = *(const uint2*)((const char*)xb + (size_t)s0 * 256 + sub * 8);
    uint2 u1 = *(const uint2*)((const char*)xb + (size_t)s1 * 256 + sub * 8);
    uint2 u2 = *(const uint2*)((const char*)xb + (size_t)s2 * 256 + sub * 8);
    uint2 u3 = *(const uint2*)((const char*)xb + (size_t)s3 * 256 + sub * 8);
    a0 += (bflo(u0.x) + bflo(u1.x)) + (bflo(u2.x) + bflo(u3.x));
    a1 += (bfhi(u0.x) + bfhi(u1.x)) + (bfhi(u2.x) + bfhi(u3.x));
    a2 += (bflo(u0.y) + bflo(u1.y)) + (bflo(u2.y) + bflo(u3.y));
    a3 += (bfhi(u0.y) + bfhi(u1.y)) + (bfhi(u2.y) + bfhi(u3.y));
  }
  for (; e < end; ++e) {
    uint2 u = *(const uint2*)((const char*)xb + (size_t)esrc[e] * 256 + sub * 8);
    a0 += bflo(u.x);
    a1 += bfhi(u.x);
    a2 += bflo(u.y);
    a3 += bfhi(u.y);
  }
  float id = invdeg[node];
  uint2 o;
  o.x = pack_bf16(a0 * id, a1 * id);
  o.y = pack_bf16(a2 * id, a3 * id);
  *(uint2*)((char*)aggb + (size_t)node * 256 + sub * 8) = o;
}

// ---------------- MFMA: pre = L2norm([aggb|xb] @ [Wl|Wr]^T + bl), BN stats ----------------
__global__ __launch_bounds__(512, 4) void mfma_pre_kernel(
    const ushort* __restrict__ aggb, const ushort* __restrict__ xb,
    const unsigned* __restrict__ wpackL, const float* __restrict__ bl,
    uint4* __restrict__ prebn,
    float* __restrict__ colsum, float* __restrict__ colsumsq) {
  __shared__ unsigned Bsw[16384];   // 64 KB
  __shared__ float lsum[HD], lsq[HD];
  const int tid = threadIdx.x;
  {
    const uint4* s = (const uint4*)wpackL;
    uint4* d = (uint4*)Bsw;
#pragma unroll
    for (int i = 0; i < 8; ++i) d[tid + i * 512] = s[tid + i * 512];
  }
  if (tid < HD) { lsum[tid] = 0.f; lsq[tid] = 0.f; }

  const int wave = tid >> 6, lane = tid & 63;
  const int lhi = lane >> 4, llo = lane & 15;
  int arow = blockIdx.x * 128 + wave * 16 + llo;
  if (arow >= NN) arow = NN - 1;
  const size_t rb = (size_t)arow * 256;

  uint4 areg[8];
#pragma unroll
  for (int ks = 0; ks < 4; ++ks) {
    areg[ks]     = *(const uint4*)((const char*)aggb + rb + ks * 64 + lhi * 16);
    areg[ks + 4] = *(const uint4*)((const char*)xb   + rb + ks * 64 + lhi * 16);
  }

  f32x4 acc[8];
#pragma unroll
  for (int ct = 0; ct < 8; ++ct) {
    float b = bl[ct * 16 + llo];
    acc[ct] = (f32x4){b, b, b, b};
  }
  __syncthreads();

#pragma unroll
  for (int ks = 0; ks < 8; ++ks) {
    bf16x8 a = __builtin_bit_cast(bf16x8, areg[ks]);
#pragma unroll
    for (int ct = 0; ct < 8; ++ct) {
      int bcol = ct * 16 + llo;
      unsigned bb = (unsigned)(bcol * 512 + ks * 64 + lhi * 16) ^ (unsigned)((bcol & 7) << 4);
      bf16x8 b = *(const bf16x8*)((const char*)Bsw + bb);
      acc[ct] = __builtin_amdgcn_mfma_f32_16x16x32_bf16(a, b, acc[ct], 0, 0, 0);
    }
  }

  float cs[8] = {0, 0, 0, 0, 0, 0, 0, 0}, cq[8] = {0, 0, 0, 0, 0, 0, 0, 0};
#pragma unroll
  for (int r = 0; r < 4; ++r) {
    int orow = blockIdx.x * 128 + wave * 16 + lhi * 4 + r;
    float p[8];
    float ss = 0.f;
#pragma unroll
    for (int ct = 0; ct < 8; ++ct) { p[ct] = acc[ct][r]; ss += p[ct] * p[ct]; }
#pragma unroll
    for (int m = 8; m >= 1; m >>= 1) ss += __shfl_xor(ss, m, 64);
    float inv = 1.0f / fmaxf(sqrtf(ss), EPS_NORM);
#pragma unroll
    for (int ct = 0; ct < 8; ++ct) p[ct] *= inv;
    uint4 o;
    o.x = pack_bf16(p[0], p[1]);
    o.y = pack_bf16(p[2], p[3]);
    o.z = pack_bf16(p[4], p[5]);
    o.w = pack_bf16(p[6], p[7]);
    prebn[((size_t)blockIdx.x * 32 + wave * 4 + r) * 64 + lane] = o;
    if (orow < NN) {
#pragma unroll
      for (int ct = 0; ct < 8; ++ct) { cs[ct] += p[ct]; cq[ct] += p[ct] * p[ct]; }
    }
  }
#pragma unroll
  for (int ct = 0; ct < 8; ++ct) {
    atomicAdd(&lsum[ct * 16 + llo], cs[ct]);
    atomicAdd(&lsq[ct * 16 + llo], cq[ct]);
  }
  __syncthreads();
  if (tid < HD) {
    atomicAdd(&colsum[tid], lsum[tid]);
    atomicAdd(&colsumsq[tid], lsq[tid]);
  }
}

// ---------------- MFMA + inline BN finalize: out = lrelu(BN(pre)) + xb@Ws^T + bs ----------------
// Each block redundantly computes scale/shift from colsum/colsumsq (removes finalize dispatch).
__global__ __launch_bounds__(512, 4) void res_mfma_kernel(
    ushort* __restrict__ xb, const uint4* __restrict__ prebn,
    const unsigned* __restrict__ wpackS, const float* __restrict__ bs,
    const float* __restrict__ colsum, const float* __restrict__ colsumsq,
    const float* __restrict__ gamma, const float* __restrict__ beta,
    float* __restrict__ outf, int last) {
  __shared__ unsigned Bsw[8192];   // 32 KB
  __shared__ float lscale[HD], lshift[HD];
  const int tid = threadIdx.x;
  {
    const uint4* s = (const uint4*)wpackS;
    uint4* d = (uint4*)Bsw;
#pragma unroll
    for (int i = 0; i < 4; ++i) d[tid + i * 512] = s[tid + i * 512];
  }
  if (tid < HD) {
    float mu = colsum[tid] * (1.0f / NN);
    float ex2 = colsumsq[tid] * (1.0f / NN);
    float var = ex2 - mu * mu;
    float sc = gamma[tid] * rsqrtf(var + EPS_BN);
    lscale[tid] = sc;
    lshift[tid] = beta[tid] - mu * sc;
  }

  const int wave = tid >> 6, lane = tid & 63;
  const int lhi = lane >> 4, llo = lane & 15;
  int arow = blockIdx.x * 128 + wave * 16 + llo;
  if (arow >= NN) arow = NN - 1;
  const size_t rb = (size_t)arow * 256;

  uint4 areg[4];
#pragma unroll
  for (int ks = 0; ks < 4; ++ks)
    areg[ks] = *(const uint4*)((const char*)xb + rb + ks * 64 + lhi * 16);
  uint4 pv4[4];
#pragma unroll
  for (int r = 0; r < 4; ++r)
    pv4[r] = prebn[((size_t)blockIdx.x * 32 + wave * 4 + r) * 64 + lane];

  f32x4 acc[8];
#pragma unroll
  for (int ct = 0; ct < 8; ++ct) {
    float b = bs[ct * 16 + llo];
    acc[ct] = (f32x4){b, b, b, b};
  }
  __syncthreads();

  float sc8[8], sh8[8];
#pragma unroll
  for (int ct = 0; ct < 8; ++ct) {
    int C = ct * 16 + llo;
    sc8[ct] = lscale[C];
    sh8[ct] = lshift[C];
  }

#pragma unroll
  for (int ks = 0; ks < 4; ++ks) {
    bf16x8 a = __builtin_bit_cast(bf16x8, areg[ks]);
#pragma unroll
    for (int ct = 0; ct < 8; ++ct) {
      int bcol = ct * 16 + llo;
      unsigned bb = (unsigned)(bcol * 256 + ks * 64 + lhi * 16) ^ (unsigned)((bcol & 7) << 4);
      bf16x8 b = *(const bf16x8*)((const char*)Bsw + bb);
      acc[ct] = __builtin_amdgcn_mfma_f32_16x16x32_bf16(a, b, acc[ct], 0, 0, 0);
    }
  }

#pragma unroll
  for (int r = 0; r < 4; ++r) {
    int orow = blockIdx.x * 128 + wave * 16 + lhi * 4 + r;
    if (orow < NN) {
      const unsigned* pw = (const unsigned*)&pv4[r];
#pragma unroll
      for (int ct = 0; ct < 8; ++ct) {
        unsigned w = pw[ct >> 1];
        float pv = (ct & 1) ? bfhi(w) : bflo(w);
        float v = pv * sc8[ct] + sh8[ct];
        v = v >= 0.f ? v : NEG_SLOPE * v;
        float o = v + acc[ct][r];
        if (last) outf[(size_t)orow * HD + ct * 16 + llo] = o;
        else      xb[(size_t)orow * HD + ct * 16 + llo] = bf16of(o);
      }
    }
  }
}

extern "C" void kernel_launch(void* const* d_in, const int* in_sizes, int n_in,
                              void* d_out, int out_size, void* d_ws, size_t ws_size,
                              hipStream_t stream) {
  const float* x0    = (const float*)d_in[0];
  const int*   ei    = (const int*)d_in[1];
  const float* Wl    = (const float*)d_in[2];
  const float* bl    = (const float*)d_in[3];
  const float* Wr    = (const float*)d_in[4];
  const float* gamma = (const float*)d_in[5];
  const float* beta  = (const float*)d_in[6];
  const float* Wsm   = (const float*)d_in[7];
  const float* bs    = (const float*)d_in[8];
  float* out = (float*)d_out;

  char* w = (char*)d_ws;
  ushort* aggb = (ushort*)w;        w += (size_t)NN * HD * 2;            // 12.8 MB
  ushort* xb   = (ushort*)w;        w += (size_t)NN * HD * 2;            // 12.8 MB
  uint4* prebn = (uint4*)w;         w += (size_t)NTILES * 32 * 64 * 16;  // 12.81 MB
  unsigned* wpackL = (unsigned*)w;  w += (size_t)NL * 16384 * 4;         // 192 KB
  unsigned* wpackS = (unsigned*)w;  w += 8192 * 4;                       // 32 KB
  float* invdeg = (float*)w;        w += (size_t)NN * 4;
  float* colsum = (float*)w;        w += HD * 4;
  float* colsumsq = (float*)w;      w += HD * 4;
  int* degi = (int*)w;              w += (size_t)NN * 4;
  int* rowptr = (int*)w;            w += (size_t)(NN + 1) * 4;
  int* cursor = (int*)w;            w += (size_t)NN * 4;
  int* blocksum = (int*)w;          w += SCAN_BLOCKS * 4;
  int* blockoff = (int*)w;          w += SCAN_BLOCKS * 4;
  int* esrc = (int*)w;              w += (size_t)NE * 4;

  const int* srcp = ei;
  const int* dstp = ei + NE;

  // one-time: CSR build + bf16 convert + weight pre-pack
  hipMemsetAsync(degi, 0, NN * sizeof(int), stream);
  hist_kernel<<<(NE + 255) / 256, 256, 0, stream>>>(dstp, degi);
  blocksum_kernel<<<SCAN_BLOCKS, 256, 0, stream>>>(degi, blocksum);
  blockscan_kernel<<<1, 256, 0, stream>>>(blocksum, blockoff, rowptr);
  chunkscan_kernel<<<SCAN_BLOCKS, 256, 0, stream>>>(degi, blockoff, rowptr, cursor, invdeg);
  fill_kernel<<<(NE + 255) / 256, 256, 0, stream>>>(srcp, dstp, cursor, esrc);
  tobf16_kernel<<<(NN * 64 + 255) / 256, 256, 0, stream>>>(x0, xb);
  packW_kernel<<<(NL * 16384 + 8192 + 255) / 256, 256, 0, stream>>>(Wl, Wr, Wsm, wpackL, wpackS);

  const int aggBlocks = ((NN + 1) / 2 * 64 + 511) / 512;   // 2 nodes/wave
  for (int l = 0; l < NL; ++l) {
    agg_csr_kernel<<<aggBlocks, 512, 0, stream>>>(xb, rowptr, esrc, invdeg, aggb,
                                                  colsum, colsumsq);
    mfma_pre_kernel<<<NTILES, 512, 0, stream>>>(aggb, xb, wpackL + (size_t)l * 16384,
                                                bl + (size_t)l * HD, prebn, colsum, colsumsq);
    res_mfma_kernel<<<NTILES, 512, 0, stream>>>(xb, prebn, wpackS, bs,
                                                colsum, colsumsq,
                                                gamma + (size_t)l * HD, beta + (size_t)l * HD,
                                                out, l == NL - 1 ? 1 : 0);
  }
}

// Round 15
// 317.573 us; speedup vs baseline: 17.6681x; 1.0738x over previous
//
#include <hip/hip_runtime.h>
#include <hip/hip_bf16.h>
#include <stdint.h>

#define NN 50000
#define NE 800000
#define HD 128
#define NL 3
#define EPS_BN 1e-5f
#define EPS_NORM 1e-12f
#define NEG_SLOPE 0.1f

#define SCAN_CHUNK 256
#define SCAN_BLOCKS ((NN + SCAN_CHUNK - 1) / SCAN_CHUNK)   // 196
#define NTILES ((NN + 127) / 128)                          // 391

#define BSH 9                                   // coarse bucket = dst >> 9 (512 nodes)
#define NB ((NN + (1 << BSH) - 1) >> BSH)       // 98 buckets
#define MAXBE 9728                              // per-bucket edge cap (mean 8192, +17 sigma)

typedef __attribute__((ext_vector_type(8))) short bf16x8;
typedef __attribute__((ext_vector_type(4))) float f32x4;

static __device__ __forceinline__ unsigned pack_bf16(float a, float b) {
  unsigned ua = __builtin_bit_cast(unsigned, a);
  unsigned ub = __builtin_bit_cast(unsigned, b);
  ua = (ua + 0x7fffu + ((ua >> 16) & 1u)) >> 16;   // RNE
  ub = (ub + 0x7fffu + ((ub >> 16) & 1u)) >> 16;
  return ua | (ub << 16);
}
static __device__ __forceinline__ ushort bf16of(float f) {
  unsigned u = __builtin_bit_cast(unsigned, f);
  u = (u + 0x7fffu + ((u >> 16) & 1u)) >> 16;
  return (ushort)u;
}
static __device__ __forceinline__ float bflo(unsigned u) { return __builtin_bit_cast(float, u << 16); }
static __device__ __forceinline__ float bfhi(unsigned u) { return __builtin_bit_cast(float, u & 0xffff0000u); }

// ---------------- CSR build ----------------
__global__ __launch_bounds__(256) void hist_kernel(const int* __restrict__ dst, int* __restrict__ degi) {
  int i = blockIdx.x * 256 + threadIdx.x;
  if (i < NE) atomicAdd(&degi[dst[i]], 1);
}

__global__ __launch_bounds__(256) void blocksum_kernel(const int* __restrict__ degi,
                                                       int* __restrict__ blocksum) {
  __shared__ int sh[256];
  int t = threadIdx.x;
  int i = blockIdx.x * 256 + t;
  sh[t] = (i < NN) ? degi[i] : 0;
  __syncthreads();
  for (int off = 128; off >= 1; off >>= 1) {
    if (t < off) sh[t] += sh[t + off];
    __syncthreads();
  }
  if (t == 0) blocksum[blockIdx.x] = sh[0];
}

__global__ __launch_bounds__(256) void blockscan_kernel(int* __restrict__ blocksum,
                                                        int* __restrict__ blockoff,
                                                        int* __restrict__ rowptr) {
  __shared__ int sh[256];
  int t = threadIdx.x;
  int v = (t < SCAN_BLOCKS) ? blocksum[t] : 0;
  sh[t] = v;
  __syncthreads();
  for (int off = 1; off < 256; off <<= 1) {
    int u = (t >= off) ? sh[t - off] : 0;
    __syncthreads();
    sh[t] += u;
    __syncthreads();
  }
  if (t < SCAN_BLOCKS) blockoff[t] = sh[t] - v;
  if (t == 255) rowptr[NN] = sh[255];
}

// also seeds bcursor[c] = rowptr[c*512] for the bucket scatter
__global__ __launch_bounds__(256) void chunkscan_kernel(const int* __restrict__ degi,
                                                        const int* __restrict__ blockoff,
                                                        int* __restrict__ rowptr,
                                                        int* __restrict__ bcursor,
                                                        float* __restrict__ invdeg) {
  __shared__ int sh[256];
  int t = threadIdx.x;
  int i = blockIdx.x * 256 + t;
  int d = (i < NN) ? degi[i] : 0;
  sh[t] = d;
  __syncthreads();
  for (int off = 1; off < 256; off <<= 1) {
    int u = (t >= off) ? sh[t - off] : 0;
    __syncthreads();
    sh[t] += u;
    __syncthreads();
  }
  if (i < NN) {
    int pre = blockoff[blockIdx.x] + sh[t] - d;
    rowptr[i] = pre;
    if ((i & ((1 << BSH) - 1)) == 0) bcursor[i >> BSH] = pre;
    invdeg[i] = 1.0f / fmaxf((float)d, 1.0f);
  }
}

// ---------------- Phase B: group edges by coarse bucket (grouped runs -> low write amp) ----------------
__global__ __launch_bounds__(1024) void bucketB_kernel(const int* __restrict__ src,
                                                       const int* __restrict__ dst,
                                                       int* __restrict__ bcursor,
                                                       uint2* __restrict__ bpack) {
  __shared__ int hist[NB], lstart[NB], gbase[NB];
  __shared__ uint2 sdat[1024];
  const int tid = threadIdx.x;
  const int e = blockIdx.x * 1024 + tid;
  if (tid < NB) hist[tid] = 0;
  __syncthreads();
  int s = 0, d = 0, b = 0, myIdx = 0;
  bool valid = (e < NE);
  if (valid) {
    s = src[e];
    d = dst[e];
    b = d >> BSH;
    myIdx = atomicAdd(&hist[b], 1);
  }
  __syncthreads();
  if (tid == 0) {
    int run = 0;
    for (int i = 0; i < NB; ++i) { lstart[i] = run; run += hist[i]; }
  }
  __syncthreads();
  if (tid < NB && hist[tid] > 0) gbase[tid] = atomicAdd(&bcursor[tid], hist[tid]);
  __syncthreads();
  if (valid) sdat[lstart[b] + myIdx] = make_uint2((unsigned)s, (unsigned)d);
  __syncthreads();
  int tot = lstart[NB - 1] + hist[NB - 1];
  if (tid < tot) {
    uint2 p = sdat[tid];
    int bb = (int)(p.y >> BSH);
    bpack[gbase[bb] + (tid - lstart[bb])] = p;
  }
}

// ---------------- Phase C: per-bucket LDS counting sort -> contiguous esrc write ----------------
__global__ __launch_bounds__(1024) void bucketC_kernel(const int* __restrict__ rowptr,
                                                       const uint2* __restrict__ bpack,
                                                       int* __restrict__ esrc) {
  __shared__ int lcur[1 << BSH];
  __shared__ int lsrc[MAXBE];
  const int c = blockIdx.x, tid = threadIdx.x;
  const int nbase = c << BSH;
  const int nend = min(nbase + (1 << BSH), NN);
  const int ebase = rowptr[nbase];
  const int cnt = rowptr[nend] - ebase;
  if (tid < (1 << BSH)) {
    int n = nbase + tid;
    lcur[tid] = (n < nend) ? rowptr[n] - ebase : 0;
  }
  __syncthreads();
  for (int i = tid; i < cnt; i += 1024) {
    uint2 p = bpack[ebase + i];
    int pos = atomicAdd(&lcur[(int)p.y - nbase], 1);
    if (pos < MAXBE) lsrc[pos] = (int)p.x;
  }
  __syncthreads();
  for (int i = tid; i < cnt; i += 1024) esrc[ebase + i] = lsrc[i];
}

// ---------------- f32 -> bf16 convert ----------------
__global__ __launch_bounds__(256) void tobf16_kernel(const float* __restrict__ x, ushort* __restrict__ xb) {
  int i = blockIdx.x * 256 + threadIdx.x;
  if (i < NN * 64) {
    float2 f = *(const float2*)(x + (size_t)i * 2);
    *(unsigned*)(xb + (size_t)i * 2) = pack_bf16(f.x, f.y);
  }
}

// ---------------- one-time weight pre-pack (swizzled bf16 LDS images) ----------------
__global__ __launch_bounds__(256) void packW_kernel(const float* __restrict__ Wl,
                                                    const float* __restrict__ Wr,
                                                    const float* __restrict__ Wsm,
                                                    unsigned* __restrict__ wpackL,
                                                    unsigned* __restrict__ wpackS) {
  int i = blockIdx.x * 256 + threadIdx.x;
  if (i < NL * 16384) {
    int l = i >> 14, rem = i & 16383;
    int c = rem >> 7, kp = rem & 127;
    int k2 = kp * 2;
    float f0, f1;
    if (k2 < HD) { const float* W = Wl + (size_t)l * HD * HD + c * HD + k2; f0 = W[0]; f1 = W[1]; }
    else         { const float* W = Wr + (size_t)l * HD * HD + c * HD + (k2 - HD); f0 = W[0]; f1 = W[1]; }
    unsigned ba = (unsigned)(c * 512 + kp * 4) ^ (unsigned)((c & 7) << 4);
    *(unsigned*)((char*)(wpackL + (size_t)l * 16384) + ba) = pack_bf16(f0, f1);
  } else if (i < NL * 16384 + 8192) {
    int j = i - NL * 16384;
    int c = j >> 6, kp = j & 63;
    int k2 = kp * 2;
    unsigned ba = (unsigned)(c * 256 + kp * 4) ^ (unsigned)((c & 7) << 4);
    *(unsigned*)((char*)wpackS + ba) = pack_bf16(Wsm[c * HD + k2], Wsm[c * HD + k2 + 1]);
  }
}

// ---------------- gather-side aggregation: 2 nodes per wave, uint2 loads ----------------
// Block 0 also zeroes the BN stat accumulators.
__global__ __launch_bounds__(512) void agg_csr_kernel(const ushort* __restrict__ xb,
                                                      const int* __restrict__ rowptr,
                                                      const int* __restrict__ esrc,
                                                      const float* __restrict__ invdeg,
                                                      ushort* __restrict__ aggb,
                                                      float* __restrict__ colsum,
                                                      float* __restrict__ colsumsq) {
  if (blockIdx.x == 0 && threadIdx.x < 2 * HD) {
    if (threadIdx.x < HD) colsum[threadIdx.x] = 0.f;
    else colsumsq[threadIdx.x - HD] = 0.f;
  }
  int wid = (blockIdx.x * 512 + threadIdx.x) >> 6;
  int lane = threadIdx.x & 63;
  int half = lane >> 5, sub = lane & 31;
  int node = wid * 2 + half;
  if (node >= NN) return;
  int start = rowptr[node], end = rowptr[node + 1];
  float a0 = 0.f, a1 = 0.f, a2 = 0.f, a3 = 0.f;
  int e = start;
  for (; e + 4 <= end; e += 4) {
    int s0 = esrc[e], s1 = esrc[e + 1], s2 = esrc[e + 2], s3 = esrc[e + 3];
    uint2 u0 = *(const uint2*)((const char*)xb + (size_t)s0 * 256 + sub * 8);
    uint2 u1 = *(const uint2*)((const char*)xb + (size_t)s1 * 256 + sub * 8);
    uint2 u2 = *(const uint2*)((const char*)xb + (size_t)s2 * 256 + sub * 8);
    uint2 u3 = *(const uint2*)((const char*)xb + (size_t)s3 * 256 + sub * 8);
    a0 += (bflo(u0.x) + bflo(u1.x)) + (bflo(u2.x) + bflo(u3.x));
    a1 += (bfhi(u0.x) + bfhi(u1.x)) + (bfhi(u2.x) + bfhi(u3.x));
    a2 += (bflo(u0.y) + bflo(u1.y)) + (bflo(u2.y) + bflo(u3.y));
    a3 += (bfhi(u0.y) + bfhi(u1.y)) + (bfhi(u2.y) + bfhi(u3.y));
  }
  for (; e < end; ++e) {
    uint2 u = *(const uint2*)((const char*)xb + (size_t)esrc[e] * 256 + sub * 8);
    a0 += bflo(u.x);
    a1 += bfhi(u.x);
    a2 += bflo(u.y);
    a3 += bfhi(u.y);
  }
  float id = invdeg[node];
  uint2 o;
  o.x = pack_bf16(a0 * id, a1 * id);
  o.y = pack_bf16(a2 * id, a3 * id);
  *(uint2*)((char*)aggb + (size_t)node * 256 + sub * 8) = o;
}

// ---------------- MFMA: pre = L2norm([aggb|xb] @ [Wl|Wr]^T + bl), BN stats ----------------
__global__ __launch_bounds__(512, 4) void mfma_pre_kernel(
    const ushort* __restrict__ aggb, const ushort* __restrict__ xb,
    const unsigned* __restrict__ wpackL, const float* __restrict__ bl,
    uint4* __restrict__ prebn,
    float* __restrict__ colsum, float* __restrict__ colsumsq) {
  __shared__ unsigned Bsw[16384];   // 64 KB
  __shared__ float lsum[HD], lsq[HD];
  const int tid = threadIdx.x;
  {
    const uint4* s = (const uint4*)wpackL;
    uint4* d = (uint4*)Bsw;
#pragma unroll
    for (int i = 0; i < 8; ++i) d[tid + i * 512] = s[tid + i * 512];
  }
  if (tid < HD) { lsum[tid] = 0.f; lsq[tid] = 0.f; }

  const int wave = tid >> 6, lane = tid & 63;
  const int lhi = lane >> 4, llo = lane & 15;
  int arow = blockIdx.x * 128 + wave * 16 + llo;
  if (arow >= NN) arow = NN - 1;
  const size_t rb = (size_t)arow * 256;

  uint4 areg[8];
#pragma unroll
  for (int ks = 0; ks < 4; ++ks) {
    areg[ks]     = *(const uint4*)((const char*)aggb + rb + ks * 64 + lhi * 16);
    areg[ks + 4] = *(const uint4*)((const char*)xb   + rb + ks * 64 + lhi * 16);
  }

  f32x4 acc[8];
#pragma unroll
  for (int ct = 0; ct < 8; ++ct) {
    float b = bl[ct * 16 + llo];
    acc[ct] = (f32x4){b, b, b, b};
  }
  __syncthreads();

#pragma unroll
  for (int ks = 0; ks < 8; ++ks) {
    bf16x8 a = __builtin_bit_cast(bf16x8, areg[ks]);
#pragma unroll
    for (int ct = 0; ct < 8; ++ct) {
      int bcol = ct * 16 + llo;
      unsigned bb = (unsigned)(bcol * 512 + ks * 64 + lhi * 16) ^ (unsigned)((bcol & 7) << 4);
      bf16x8 b = *(const bf16x8*)((const char*)Bsw + bb);
      acc[ct] = __builtin_amdgcn_mfma_f32_16x16x32_bf16(a, b, acc[ct], 0, 0, 0);
    }
  }

  float cs[8] = {0, 0, 0, 0, 0, 0, 0, 0}, cq[8] = {0, 0, 0, 0, 0, 0, 0, 0};
#pragma unroll
  for (int r = 0; r < 4; ++r) {
    int orow = blockIdx.x * 128 + wave * 16 + lhi * 4 + r;
    float p[8];
    float ss = 0.f;
#pragma unroll
    for (int ct = 0; ct < 8; ++ct) { p[ct] = acc[ct][r]; ss += p[ct] * p[ct]; }
#pragma unroll
    for (int m = 8; m >= 1; m >>= 1) ss += __shfl_xor(ss, m, 64);
    float inv = 1.0f / fmaxf(sqrtf(ss), EPS_NORM);
#pragma unroll
    for (int ct = 0; ct < 8; ++ct) p[ct] *= inv;
    uint4 o;
    o.x = pack_bf16(p[0], p[1]);
    o.y = pack_bf16(p[2], p[3]);
    o.z = pack_bf16(p[4], p[5]);
    o.w = pack_bf16(p[6], p[7]);
    prebn[((size_t)blockIdx.x * 32 + wave * 4 + r) * 64 + lane] = o;
    if (orow < NN) {
#pragma unroll
      for (int ct = 0; ct < 8; ++ct) { cs[ct] += p[ct]; cq[ct] += p[ct] * p[ct]; }
    }
  }
#pragma unroll
  for (int ct = 0; ct < 8; ++ct) {
    atomicAdd(&lsum[ct * 16 + llo], cs[ct]);
    atomicAdd(&lsq[ct * 16 + llo], cq[ct]);
  }
  __syncthreads();
  if (tid < HD) {
    atomicAdd(&colsum[tid], lsum[tid]);
    atomicAdd(&colsumsq[tid], lsq[tid]);
  }
}

// ---------------- MFMA + inline BN finalize: out = lrelu(BN(pre)) + xb@Ws^T + bs ----------------
__global__ __launch_bounds__(512, 4) void res_mfma_kernel(
    ushort* __restrict__ xb, const uint4* __restrict__ prebn,
    const unsigned* __restrict__ wpackS, const float* __restrict__ bs,
    const float* __restrict__ colsum, const float* __restrict__ colsumsq,
    const float* __restrict__ gamma, const float* __restrict__ beta,
    float* __restrict__ outf, int last) {
  __shared__ unsigned Bsw[8192];   // 32 KB
  __shared__ float lscale[HD], lshift[HD];
  const int tid = threadIdx.x;
  {
    const uint4* s = (const uint4*)wpackS;
    uint4* d = (uint4*)Bsw;
#pragma unroll
    for (int i = 0; i < 4; ++i) d[tid + i * 512] = s[tid + i * 512];
  }
  if (tid < HD) {
    float mu = colsum[tid] * (1.0f / NN);
    float ex2 = colsumsq[tid] * (1.0f / NN);
    float var = ex2 - mu * mu;
    float sc = gamma[tid] * rsqrtf(var + EPS_BN);
    lscale[tid] = sc;
    lshift[tid] = beta[tid] - mu * sc;
  }

  const int wave = tid >> 6, lane = tid & 63;
  const int lhi = lane >> 4, llo = lane & 15;
  int arow = blockIdx.x * 128 + wave * 16 + llo;
  if (arow >= NN) arow = NN - 1;
  const size_t rb = (size_t)arow * 256;

  uint4 areg[4];
#pragma unroll
  for (int ks = 0; ks < 4; ++ks)
    areg[ks] = *(const uint4*)((const char*)xb + rb + ks * 64 + lhi * 16);
  uint4 pv4[4];
#pragma unroll
  for (int r = 0; r < 4; ++r)
    pv4[r] = prebn[((size_t)blockIdx.x * 32 + wave * 4 + r) * 64 + lane];

  f32x4 acc[8];
#pragma unroll
  for (int ct = 0; ct < 8; ++ct) {
    float b = bs[ct * 16 + llo];
    acc[ct] = (f32x4){b, b, b, b};
  }
  __syncthreads();

  float sc8[8], sh8[8];
#pragma unroll
  for (int ct = 0; ct < 8; ++ct) {
    int C = ct * 16 + llo;
    sc8[ct] = lscale[C];
    sh8[ct] = lshift[C];
  }

#pragma unroll
  for (int ks = 0; ks < 4; ++ks) {
    bf16x8 a = __builtin_bit_cast(bf16x8, areg[ks]);
#pragma unroll
    for (int ct = 0; ct < 8; ++ct) {
      int bcol = ct * 16 + llo;
      unsigned bb = (unsigned)(bcol * 256 + ks * 64 + lhi * 16) ^ (unsigned)((bcol & 7) << 4);
      bf16x8 b = *(const bf16x8*)((const char*)Bsw + bb);
      acc[ct] = __builtin_amdgcn_mfma_f32_16x16x32_bf16(a, b, acc[ct], 0, 0, 0);
    }
  }

#pragma unroll
  for (int r = 0; r < 4; ++r) {
    int orow = blockIdx.x * 128 + wave * 16 + lhi * 4 + r;
    if (orow < NN) {
      const unsigned* pw = (const unsigned*)&pv4[r];
#pragma unroll
      for (int ct = 0; ct < 8; ++ct) {
        unsigned w = pw[ct >> 1];
        float pv = (ct & 1) ? bfhi(w) : bflo(w);
        float v = pv * sc8[ct] + sh8[ct];
        v = v >= 0.f ? v : NEG_SLOPE * v;
        float o = v + acc[ct][r];
        if (last) outf[(size_t)orow * HD + ct * 16 + llo] = o;
        else      xb[(size_t)orow * HD + ct * 16 + llo] = bf16of(o);
      }
    }
  }
}

extern "C" void kernel_launch(void* const* d_in, const int* in_sizes, int n_in,
                              void* d_out, int out_size, void* d_ws, size_t ws_size,
                              hipStream_t stream) {
  const float* x0    = (const float*)d_in[0];
  const int*   ei    = (const int*)d_in[1];
  const float* Wl    = (const float*)d_in[2];
  const float* bl    = (const float*)d_in[3];
  const float* Wr    = (const float*)d_in[4];
  const float* gamma = (const float*)d_in[5];
  const float* beta  = (const float*)d_in[6];
  const float* Wsm   = (const float*)d_in[7];
  const float* bs    = (const float*)d_in[8];
  float* out = (float*)d_out;

  char* w = (char*)d_ws;
  ushort* aggb = (ushort*)w;        w += (size_t)NN * HD * 2;            // 12.8 MB
  ushort* xb   = (ushort*)w;        w += (size_t)NN * HD * 2;            // 12.8 MB
  uint4* prebn = (uint4*)w;         w += (size_t)NTILES * 32 * 64 * 16;  // 12.81 MB
  unsigned* wpackL = (unsigned*)w;  w += (size_t)NL * 16384 * 4;         // 192 KB
  unsigned* wpackS = (unsigned*)w;  w += 8192 * 4;                       // 32 KB
  float* invdeg = (float*)w;        w += (size_t)NN * 4;
  float* colsum = (float*)w;        w += HD * 4;
  float* colsumsq = (float*)w;      w += HD * 4;
  int* degi = (int*)w;              w += (size_t)NN * 4;
  int* rowptr = (int*)w;            w += (size_t)(NN + 1) * 4;
  int* bcursor = (int*)w;           w += (size_t)(NB + 8) * 4;
  int* blocksum = (int*)w;          w += SCAN_BLOCKS * 4;
  int* blockoff = (int*)w;          w += SCAN_BLOCKS * 4;
  uint2* bpack = (uint2*)w;         w += (size_t)NE * 8;                 // 6.4 MB
  int* esrc = (int*)w;              w += (size_t)NE * 4;                 // 3.2 MB

  const int* srcp = ei;
  const int* dstp = ei + NE;

  // one-time: CSR build (low-write-amp two-phase sort) + bf16 convert + weight pre-pack
  hipMemsetAsync(degi, 0, NN * sizeof(int), stream);
  hist_kernel<<<(NE + 255) / 256, 256, 0, stream>>>(dstp, degi);
  blocksum_kernel<<<SCAN_BLOCKS, 256, 0, stream>>>(degi, blocksum);
  blockscan_kernel<<<1, 256, 0, stream>>>(blocksum, blockoff, rowptr);
  chunkscan_kernel<<<SCAN_BLOCKS, 256, 0, stream>>>(degi, blockoff, rowptr, bcursor, invdeg);
  bucketB_kernel<<<(NE + 1023) / 1024, 1024, 0, stream>>>(srcp, dstp, bcursor, bpack);
  bucketC_kernel<<<NB, 1024, 0, stream>>>(rowptr, bpack, esrc);
  tobf16_kernel<<<(NN * 64 + 255) / 256, 256, 0, stream>>>(x0, xb);
  packW_kernel<<<(NL * 16384 + 8192 + 255) / 256, 256, 0, stream>>>(Wl, Wr, Wsm, wpackL, wpackS);

  const int aggBlocks = ((NN + 1) / 2 * 64 + 511) / 512;   // 2 nodes/wave
  for (int l = 0; l < NL; ++l) {
    agg_csr_kernel<<<aggBlocks, 512, 0, stream>>>(xb, rowptr, esrc, invdeg, aggb,
                                                  colsum, colsumsq);
    mfma_pre_kernel<<<NTILES, 512, 0, stream>>>(aggb, xb, wpackL + (size_t)l * 16384,
                                                bl + (size_t)l * HD, prebn, colsum, colsumsq);
    res_mfma_kernel<<<NTILES, 512, 0, stream>>>(xb, prebn, wpackS, bs,
                                                colsum, colsumsq,
                                                gamma + (size_t)l * HD, beta + (size_t)l * HD,
                                                out, l == NL - 1 ? 1 : 0);
  }
}